// Round 21
// baseline (474.933 us; speedup 1.0000x reference)
//
#include <hip/hip_runtime.h>
#include <hip/hip_bf16.h>

typedef __hip_bfloat16 bf16;
typedef __attribute__((ext_vector_type(8))) short short8;
typedef __attribute__((ext_vector_type(4))) short short4v;
typedef __attribute__((ext_vector_type(4))) float f32x4;

#define C_DIM 180
#define CPAD  192
#define NHEAD 6
#define HD    30
#define HID   720
#define HPAD  768
#define QKVW  576
#define LN_EPS 1e-5f
#define IMG_TOK 16384
#define QSCALE 0.18257418583505536f

static __device__ __forceinline__ bf16 f2bf(float f) { return __float2bfloat16(f); }
static __device__ __forceinline__ float bf2f(bf16 v) { return __bfloat162float(v); }
static __device__ __forceinline__ short bfbits(float f) {
    bf16 b = __float2bfloat16(f); return *reinterpret_cast<short*>(&b);
}
static __device__ __forceinline__ float gelu_sig(float v) {
    float e = __expf(-1.702f * v);
    return v * __builtin_amdgcn_rcpf(1.f + e);
}

// ---------------- weight prep ----------------
__global__ __launch_bounds__(256) void prep_w(const float* __restrict__ w, bf16* __restrict__ bt,
                                              int K, int N, int Kpad, int Npad) {
    int idx = blockIdx.x * 256 + threadIdx.x;
    if (idx >= Kpad * Npad) return;
    int k = idx % Kpad, n = idx / Kpad;
    float v = (k < K && n < N) ? w[(long)k * N + n] : 0.f;
    bt[idx] = f2bf(v);
}

__global__ __launch_bounds__(256) void prep_wqkv(const float* __restrict__ w, bf16* __restrict__ bt) {
    int idx = blockIdx.x * 256 + threadIdx.x;   // 576*192
    if (idx >= QKVW * CPAD) return;
    int k = idx % CPAD, c = idx / CPAD;
    int mat = c / 192, rem = c % 192;
    int hh = rem >> 5, dd = rem & 31;
    float v = 0.f;
    if (dd < HD && k < C_DIM) {
        v = w[(long)k * 540 + mat * 180 + hh * 30 + dd];
        if (mat == 0) v *= QSCALE;
    }
    bt[idx] = f2bf(v);
}
__global__ __launch_bounds__(256) void prep_bqkv(const float* __restrict__ b, float* __restrict__ bp) {
    int c = blockIdx.x * 256 + threadIdx.x;
    if (c >= QKVW) return;
    int mat = c / 192, rem = c % 192;
    int hh = rem >> 5, dd = rem & 31;
    float v = 0.f;
    if (dd < HD) {
        v = b[mat * 180 + hh * 30 + dd];
        if (mat == 0) v *= QSCALE;
    }
    bp[c] = v;
}

__global__ __launch_bounds__(256) void prep_f1b(const float* __restrict__ b, float* __restrict__ bp) {
    int i = blockIdx.x * 256 + threadIdx.x;
    if (i < HPAD) bp[i] = (i < HID) ? b[i] : 0.f;
}

__global__ __launch_bounds__(256) void prep_bias(const float* __restrict__ tbl,
                                                 float* __restrict__ bias_frag) {
    int idx = blockIdx.x * 256 + threadIdx.x;   // 6144
    if (idx >= 6144) return;
    int lane = idx & 63;
    int fj = (idx >> 6) & 3;
    int fi = (idx >> 8) & 3;
    int h  = idx >> 10;
    int g = lane >> 4, l15 = lane & 15;
    int kk = fj * 16 + l15;
    int rk = kk >> 3, ck = kk & 7;
    #pragma unroll
    for (int r = 0; r < 4; ++r) {
        int q = fi * 16 + g * 4 + r;
        int rq = q >> 3, cq = q & 7;
        int bidx = (rq - rk + 7) * 15 + (cq - ck + 7);
        bias_frag[idx * 4 + r] = tbl[bidx * NHEAD + h];
    }
}

// ---------------- LayerNorm (LN1 only) ----------------
__global__ __launch_bounds__(256) void ln_kernel(const float* __restrict__ x,
                                                 const float* __restrict__ w,
                                                 const float* __restrict__ b,
                                                 bf16* __restrict__ out, int M) {
    int wave = threadIdx.x >> 6;
    int lane = threadIdx.x & 63;
    long row = (long)blockIdx.x * 4 + wave;
    if (row >= M) return;
    const float* xr = x + row * C_DIM;
    float e0 = xr[lane];
    float e1 = xr[lane + 64];
    float e2 = (lane < C_DIM - 128) ? xr[lane + 128] : 0.f;
    float s  = e0 + e1 + e2;
    float ss = e0*e0 + e1*e1 + e2*e2;
    #pragma unroll
    for (int off = 32; off > 0; off >>= 1) {
        s  += __shfl_xor(s,  off);
        ss += __shfl_xor(ss, off);
    }
    float mean = s * (1.f / C_DIM);
    float var  = ss * (1.f / C_DIM) - mean * mean;
    float rs   = rsqrtf(var + LN_EPS);
    bf16* orow = out + row * CPAD;
    orow[lane]      = f2bf((e0 - mean) * rs * w[lane]      + b[lane]);
    orow[lane + 64] = f2bf((e1 - mean) * rs * w[lane + 64] + b[lane + 64]);
    if (lane < C_DIM - 128)
        orow[lane + 128] = f2bf((e2 - mean) * rs * w[lane + 128] + b[lane + 128]);
    if (lane < CPAD - C_DIM)
        orow[C_DIM + lane] = f2bf(0.f);
}

#define GLL16(gp, lp) \
    __builtin_amdgcn_global_load_lds((const __attribute__((address_space(1))) unsigned int*)(gp), \
                                     (__attribute__((address_space(3))) unsigned int*)(lp), 16, 0, 0)

// ---------------- MFMA GEMM, 128x64 tile (QKV) ----------------
__global__ __launch_bounds__(256) void mfma_gemm(
    const bf16* __restrict__ A, int lda,
    const bf16* __restrict__ Bt,
    const float* __restrict__ bias,
    bf16* __restrict__ out, int ldo, int nstore,
    int Kpad, int P)
{
    __shared__ __align__(16) short smem[128 * 64 + 64 * 64];
    short* As = smem;
    short* Bs = smem + 128 * 64;
    int tid  = threadIdx.x;
    int lane = tid & 63;
    int wave = tid >> 6;
    int wm = wave >> 1, wn = wave & 1;
    int g4 = lane >> 4, l15 = lane & 15;

    int flat = blockIdx.x;
    int grp  = flat / (8 * P);
    int rem  = flat - grp * 8 * P;
    int p    = rem >> 3;
    long m0  = (long)(grp * 8 + (rem & 7)) * 128;
    int  n0  = p * 64;

    f32x4 acc[4][2] = {};

    int nkt = Kpad >> 6;
    for (int kt = 0; kt < nkt; ++kt) {
        int k0 = kt << 6;
        #pragma unroll
        for (int i = 0; i < 4; ++i) {
            int f = i * 256 + tid;
            int r = f >> 3, c = f & 7;
            const bf16* gp = A + (m0 + r) * (long)lda + k0 + ((c ^ (r & 7)) << 3);
            GLL16(gp, &As[(i * 256 + (wave << 6)) * 8]);
        }
        #pragma unroll
        for (int i = 0; i < 2; ++i) {
            int f = i * 256 + tid;
            int r = f >> 3, c = f & 7;
            const bf16* gp = Bt + (n0 + r) * (long)Kpad + k0 + ((c ^ (r & 7)) << 3);
            GLL16(gp, &Bs[(i * 256 + (wave << 6)) * 8]);
        }
        __syncthreads();
        #pragma unroll
        for (int ks = 0; ks < 2; ++ks) {
            short8 af[4], bfr[2];
            #pragma unroll
            for (int fi = 0; fi < 4; ++fi) {
                int r  = wm * 64 + fi * 16 + l15;
                int ch = ks * 4 + g4;
                af[fi] = *(const short8*)&As[r * 64 + ((ch ^ (r & 7)) << 3)];
            }
            #pragma unroll
            for (int fj = 0; fj < 2; ++fj) {
                int r  = wn * 32 + fj * 16 + l15;
                int ch = ks * 4 + g4;
                bfr[fj] = *(const short8*)&Bs[r * 64 + ((ch ^ (r & 7)) << 3)];
            }
            #pragma unroll
            for (int fi = 0; fi < 4; ++fi)
                #pragma unroll
                for (int fj = 0; fj < 2; ++fj)
                    acc[fi][fj] = __builtin_amdgcn_mfma_f32_16x16x32_bf16(af[fi], bfr[fj], acc[fi][fj], 0, 0, 0);
        }
        __syncthreads();
    }

    short* Cs = smem;
    #pragma unroll
    for (int fi = 0; fi < 4; ++fi)
        #pragma unroll
        for (int fj = 0; fj < 2; ++fj) {
            int col = wn * 32 + fj * 16 + l15;
            float bv = (n0 + col < nstore) ? bias[n0 + col] : 0.f;
            #pragma unroll
            for (int rg = 0; rg < 4; ++rg) {
                int row = wm * 64 + fi * 16 + g4 * 4 + rg;
                Cs[row * 72 + col] = bfbits(acc[fi][fj][rg] + bv);
            }
        }
    __syncthreads();
    #pragma unroll
    for (int i = 0; i < 4; ++i) {
        int t = i * 256 + tid;
        int row = t >> 3, c8 = t & 7;
        short8 v = *(const short8*)&Cs[row * 72 + c8 * 8];
        *(short8*)(out + (m0 + row) * (long)ldo + n0 + c8 * 8) = v;
    }
}

// ---------------- MFMA GEMM, 128x192 single-panel, 512 threads (proj / FC2) ----------------
// 8 waves (4m x 2n), wave tile 32x96, acc[2][6]. f32 out + optional f32 resid.
// DO_LN: fused LayerNorm on the final value -> xnout bf16 [row][CPAD] (proj only).
template<int DO_LN>
__global__ __launch_bounds__(512) void mfma_gemm192(
    const bf16* __restrict__ A, int lda,
    const bf16* __restrict__ Bt,            // [192][Kpad]
    const float* __restrict__ bias,
    const float* __restrict__ resid, int nres,
    float* __restrict__ out, int ldo, int nstore,
    int Kpad,
    const float* __restrict__ lnw, const float* __restrict__ lnb,
    bf16* __restrict__ xnout)
{
    __shared__ __align__(16) short smem[128 * 64 + 192 * 64];   // 16 + 24 = 40 KB
    short* As = smem;
    short* Bs = smem + 128 * 64;
    int tid  = threadIdx.x;
    int lane = tid & 63;
    int wave = tid >> 6;
    int wm = wave >> 1, wn = wave & 1;
    int g4 = lane >> 4, l15 = lane & 15;

    int flat = blockIdx.x;
    long m0  = (long)flat * 128;

    f32x4 acc[2][6] = {};

    int nkt = Kpad >> 6;
    for (int kt = 0; kt < nkt; ++kt) {
        int k0 = kt << 6;
        #pragma unroll
        for (int i = 0; i < 2; ++i) {
            int f = i * 512 + tid;
            int r = f >> 3, c = f & 7;
            const bf16* gp = A + (m0 + r) * (long)lda + k0 + ((c ^ (r & 7)) << 3);
            GLL16(gp, &As[(i * 512 + (wave << 6)) * 8]);
        }
        #pragma unroll
        for (int i = 0; i < 3; ++i) {
            int f = i * 512 + tid;
            int r = f >> 3, c = f & 7;
            const bf16* gp = Bt + r * (long)Kpad + k0 + ((c ^ (r & 7)) << 3);
            GLL16(gp, &Bs[(i * 512 + (wave << 6)) * 8]);
        }
        __syncthreads();
        #pragma unroll
        for (int ks = 0; ks < 2; ++ks) {
            short8 af[2], bfr[6];
            #pragma unroll
            for (int fi = 0; fi < 2; ++fi) {
                int r  = wm * 32 + fi * 16 + l15;
                int ch = ks * 4 + g4;
                af[fi] = *(const short8*)&As[r * 64 + ((ch ^ (r & 7)) << 3)];
            }
            #pragma unroll
            for (int fj = 0; fj < 6; ++fj) {
                int r  = wn * 96 + fj * 16 + l15;
                int ch = ks * 4 + g4;
                bfr[fj] = *(const short8*)&Bs[r * 64 + ((ch ^ (r & 7)) << 3)];
            }
            #pragma unroll
            for (int fi = 0; fi < 2; ++fi)
                #pragma unroll
                for (int fj = 0; fj < 6; ++fj)
                    acc[fi][fj] = __builtin_amdgcn_mfma_f32_16x16x32_bf16(af[fi], bfr[fj], acc[fi][fj], 0, 0, 0);
        }
        __syncthreads();
    }

    // epilogue: 4 phases of 32 rows via f32 LDS [32][196]
    float* Cf = (float*)smem;
    int cpr = nstore >> 2;                  // 45 float4 chunks per row
    #pragma unroll
    for (int ph = 0; ph < 4; ++ph) {
        if (wm == ph) {
            #pragma unroll
            for (int fi = 0; fi < 2; ++fi)
                #pragma unroll
                for (int fj = 0; fj < 6; ++fj) {
                    int col = wn * 96 + fj * 16 + l15;
                    float bv = (col < nstore) ? bias[col] : 0.f;
                    #pragma unroll
                    for (int rg = 0; rg < 4; ++rg) {
                        int lrow = fi * 16 + g4 * 4 + rg;
                        Cf[lrow * 196 + col] = acc[fi][fj][rg] + bv;
                    }
                }
        }
        __syncthreads();
        for (int t = tid; t < 32 * cpr; t += 512) {
            int row = t / cpr, cc = (t - row * cpr) * 4;
            long grow = m0 + ph * 32 + row;
            f32x4 v = *(const f32x4*)&Cf[row * 196 + cc];
            if (resid) {
                f32x4 rv = *(const f32x4*)(resid + grow * (long)nres + cc);
                v += rv;
            }
            *(f32x4*)(out + grow * (long)ldo + cc) = v;
            if (DO_LN) *(f32x4*)&Cf[row * 196 + cc] = v;   // final x1 back to LDS for LN
        }
        __syncthreads();
        if (DO_LN) {
            // 16 threads per row (512 = 32 rows x 16), 12 cols each (16*12 = 192)
            int row = tid >> 4, sub = tid & 15;
            float s = 0.f, ss = 0.f;
            float vals[12];
            #pragma unroll
            for (int j = 0; j < 12; ++j) {
                int col = sub * 12 + j;
                float v = (col < C_DIM) ? Cf[row * 196 + col] : 0.f;
                vals[j] = v;
                s += v; ss += v * v;
            }
            #pragma unroll
            for (int mask = 1; mask <= 8; mask <<= 1) {
                s  += __shfl_xor(s,  mask);
                ss += __shfl_xor(ss, mask);
            }
            float mean = s * (1.f / C_DIM);
            float var  = ss * (1.f / C_DIM) - mean * mean;
            float rs   = rsqrtf(var + LN_EPS);
            bf16* xr = xnout + (m0 + ph * 32 + row) * CPAD;
            #pragma unroll
            for (int j = 0; j < 12; ++j) {
                int col = sub * 12 + j;
                float o = (col < C_DIM) ? (vals[j] - mean) * rs * lnw[col] + lnb[col] : 0.f;
                xr[col] = f2bf(o);
            }
            __syncthreads();               // Cf reads done before next phase overwrites
        }
    }
}

// ---------------- MFMA GEMM, 128x128 tile, 512 threads (FC1) ----------------
template<int DO_GELU>
__global__ __launch_bounds__(512) void mfma_gemm128(
    const bf16* __restrict__ A, int lda,
    const bf16* __restrict__ Bt,
    const float* __restrict__ bias,
    bf16* __restrict__ out, int ldo,
    int Kpad, int P)
{
    __shared__ __align__(16) short smem[128 * 64 + 128 * 64];
    short* As = smem;
    short* Bs = smem + 128 * 64;
    int tid  = threadIdx.x;
    int lane = tid & 63;
    int wave = tid >> 6;
    int wm = wave >> 1, wn = wave & 1;
    int g4 = lane >> 4, l15 = lane & 15;

    int flat = blockIdx.x;
    int grp  = flat / (8 * P);
    int rem  = flat - grp * 8 * P;
    int p    = rem >> 3;
    long m0  = (long)(grp * 8 + (rem & 7)) * 128;
    int  n0  = p * 128;

    f32x4 acc[2][4] = {};

    int nkt = Kpad >> 6;
    for (int kt = 0; kt < nkt; ++kt) {
        int k0 = kt << 6;
        #pragma unroll
        for (int i = 0; i < 2; ++i) {
            int f = i * 512 + tid;
            int r = f >> 3, c = f & 7;
            const bf16* gp = A + (m0 + r) * (long)lda + k0 + ((c ^ (r & 7)) << 3);
            GLL16(gp, &As[(i * 512 + (wave << 6)) * 8]);
        }
        #pragma unroll
        for (int i = 0; i < 2; ++i) {
            int f = i * 512 + tid;
            int r = f >> 3, c = f & 7;
            const bf16* gp = Bt + (n0 + r) * (long)Kpad + k0 + ((c ^ (r & 7)) << 3);
            GLL16(gp, &Bs[(i * 512 + (wave << 6)) * 8]);
        }
        __syncthreads();
        #pragma unroll
        for (int ks = 0; ks < 2; ++ks) {
            short8 af[2], bfr[4];
            #pragma unroll
            for (int fi = 0; fi < 2; ++fi) {
                int r  = wm * 32 + fi * 16 + l15;
                int ch = ks * 4 + g4;
                af[fi] = *(const short8*)&As[r * 64 + ((ch ^ (r & 7)) << 3)];
            }
            #pragma unroll
            for (int fj = 0; fj < 4; ++fj) {
                int r  = wn * 64 + fj * 16 + l15;
                int ch = ks * 4 + g4;
                bfr[fj] = *(const short8*)&Bs[r * 64 + ((ch ^ (r & 7)) << 3)];
            }
            #pragma unroll
            for (int fi = 0; fi < 2; ++fi)
                #pragma unroll
                for (int fj = 0; fj < 4; ++fj)
                    acc[fi][fj] = __builtin_amdgcn_mfma_f32_16x16x32_bf16(af[fi], bfr[fj], acc[fi][fj], 0, 0, 0);
        }
        __syncthreads();
    }

    short* Cs = smem;
    #pragma unroll
    for (int fi = 0; fi < 2; ++fi)
        #pragma unroll
        for (int fj = 0; fj < 4; ++fj) {
            int col = wn * 64 + fj * 16 + l15;
            float bv = bias[n0 + col];
            #pragma unroll
            for (int rg = 0; rg < 4; ++rg) {
                int row = wm * 32 + fi * 16 + g4 * 4 + rg;
                float v = acc[fi][fj][rg] + bv;
                if (DO_GELU) v = gelu_sig(v);
                int ch = (col >> 3) ^ (row & 7);
                Cs[row * 128 + (ch << 3) + (col & 7)] = bfbits(v);
            }
        }
    __syncthreads();
    #pragma unroll
    for (int i = 0; i < 4; ++i) {
        int t = i * 512 + tid;
        int row = t >> 4, c16 = t & 15;
        short8 v = *(const short8*)&Cs[row * 128 + ((c16 ^ (row & 7)) << 3)];
        *(short8*)(out + (m0 + row) * (long)ldo + n0 + c16 * 8) = v;
    }
}

// ---------------- MFMA window attention ----------------
__global__ __launch_bounds__(384, 3) void attn_mfma(
    const bf16* __restrict__ qkv,
    const float* __restrict__ bias_frag,
    bf16* __restrict__ o)
{
    __shared__ __align__(16) short lds[6 * 4096];
    int tid  = threadIdx.x;
    int wave = tid >> 6;
    int lane = tid & 63;
    int h = wave;
    int w = blockIdx.x;
    int b = w >> 8, rem = w & 255;
    int wi = rem >> 4, wj = rem & 15;
    long base = (long)b * IMG_TOK + wi * 8 * 128 + wj * 8;
    int g = lane >> 4, l15 = lane & 15;

    short* Vt = &lds[wave * 4096];
    short* Ph = &lds[wave * 4096 + 2048];

    short8 qf[4], kf[4];
    #pragma unroll
    for (int fi = 0; fi < 4; ++fi) {
        int q = fi * 16 + l15;
        long t = base + (q >> 3) * 128 + (q & 7);
        const bf16* rowp = qkv + t * QKVW + h * 32 + g * 8;
        qf[fi] = *(const short8*)(rowp);
        kf[fi] = *(const short8*)(rowp + 192);
    }

    {
        int t = lane;
        const bf16* vp = qkv + (base + (t >> 3) * 128 + (t & 7)) * QKVW + 384 + h * 32;
        short8 v0 = *(const short8*)(vp);
        short8 v1 = *(const short8*)(vp + 8);
        short8 v2 = *(const short8*)(vp + 16);
        short8 v3 = *(const short8*)(vp + 24);
        int ct = t >> 3, t7 = t & 7;
        #pragma unroll
        for (int d = 0; d < 8; ++d)  Vt[d * 64 + ((ct ^ d) << 3) + t7] = v0[d];
        #pragma unroll
        for (int d = 8; d < 16; ++d) Vt[d * 64 + ((ct ^ (d & 7)) << 3) + t7] = v1[d - 8];
        #pragma unroll
        for (int d = 16; d < 24; ++d) Vt[d * 64 + ((ct ^ (d & 7)) << 3) + t7] = v2[d - 16];
        #pragma unroll
        for (int d = 24; d < 32; ++d) Vt[d * 64 + ((ct ^ (d & 7)) << 3) + t7] = v3[d - 24];
    }

    f32x4 S[4][4];
    #pragma unroll
    for (int fi = 0; fi < 4; ++fi)
        #pragma unroll
        for (int fj = 0; fj < 4; ++fj)
            S[fi][fj] = *(const f32x4*)(bias_frag + (((h * 4 + fi) * 4 + fj) * 64 + lane) * 4);
    #pragma unroll
    for (int fi = 0; fi < 4; ++fi)
        #pragma unroll
        for (int fj = 0; fj < 4; ++fj)
            S[fi][fj] = __builtin_amdgcn_mfma_f32_16x16x32_bf16(qf[fi], kf[fj], S[fi][fj], 0, 0, 0);

    f32x4 mrow[4], lsum[4];
    #pragma unroll
    for (int fi = 0; fi < 4; ++fi) {
        f32x4 a = S[fi][0], c = S[fi][2];
        #pragma unroll
        for (int cc = 0; cc < 4; ++cc) {
            a[cc] = fmaxf(a[cc], S[fi][1][cc]);
            c[cc] = fmaxf(c[cc], S[fi][3][cc]);
            a[cc] = fmaxf(a[cc], c[cc]);
        }
        mrow[fi] = a;
    }
    #pragma unroll
    for (int mask = 1; mask <= 8; mask <<= 1)
        #pragma unroll
        for (int fi = 0; fi < 4; ++fi)
            #pragma unroll
            for (int cc = 0; cc < 4; ++cc)
                mrow[fi][cc] = fmaxf(mrow[fi][cc], __shfl_xor(mrow[fi][cc], mask));
    #pragma unroll
    for (int fi = 0; fi < 4; ++fi)
        #pragma unroll
        for (int fj = 0; fj < 4; ++fj)
            #pragma unroll
            for (int cc = 0; cc < 4; ++cc)
                S[fi][fj][cc] = __expf(S[fi][fj][cc] - mrow[fi][cc]);
    #pragma unroll
    for (int fi = 0; fi < 4; ++fi) {
        f32x4 a = S[fi][0] + S[fi][1];
        f32x4 c = S[fi][2] + S[fi][3];
        lsum[fi] = a + c;
    }
    #pragma unroll
    for (int mask = 1; mask <= 8; mask <<= 1)
        #pragma unroll
        for (int fi = 0; fi < 4; ++fi)
            #pragma unroll
            for (int cc = 0; cc < 4; ++cc)
                lsum[fi][cc] += __shfl_xor(lsum[fi][cc], mask);

    f32x4 O[4][2] = {};
    #pragma unroll
    for (int ks = 0; ks < 2; ++ks) {
        #pragma unroll
        for (int fi = 0; fi < 4; ++fi)
            #pragma unroll
            for (int f2 = 0; f2 < 2; ++f2) {
                int fj = ks * 2 + f2;
                int kh = f2 * 16 + l15;
                #pragma unroll
                for (int r = 0; r < 4; ++r) {
                    int q = fi * 16 + g * 4 + r;
                    int c = (kh >> 3) ^ r ^ g;
                    Ph[q * 32 + (c << 3) + (kh & 7)] = bfbits(S[fi][fj][r]);
                }
            }
        short8 vf[2];
        #pragma unroll
        for (int f2 = 0; f2 < 2; ++f2) {
            int d = f2 * 16 + l15;
            int cv = (ks * 4 + g) ^ (d & 7);
            vf[f2] = *(const short8*)&Vt[d * 64 + (cv << 3)];
        }
        #pragma unroll
        for (int fi = 0; fi < 4; ++fi) {
            int q = fi * 16 + l15;
            int cr = g ^ (q & 3) ^ ((q >> 2) & 3);
            short8 pf = *(const short8*)&Ph[q * 32 + (cr << 3)];
            #pragma unroll
            for (int f2 = 0; f2 < 2; ++f2)
                O[fi][f2] = __builtin_amdgcn_mfma_f32_16x16x32_bf16(pf, vf[f2], O[fi][f2], 0, 0, 0);
        }
    }

    #pragma unroll
    for (int fi = 0; fi < 4; ++fi) {
        f32x4 inv;
        #pragma unroll
        for (int cc = 0; cc < 4; ++cc) inv[cc] = 1.f / lsum[fi][cc];
        #pragma unroll
        for (int r = 0; r < 4; ++r) {
            int q = fi * 16 + g * 4 + r;
            long t = base + (q >> 3) * 128 + (q & 7);
            bf16* op = o + t * CPAD + h * HD;
            op[l15] = f2bf(O[fi][0][r] * inv[r]);
            if (l15 < HD - 16)
                op[16 + l15] = f2bf(O[fi][1][r] * inv[r]);
        }
    }
    if (h == 0) {
        long t = base + (lane >> 3) * 128 + (lane & 7);
        bf16* op = o + t * CPAD + C_DIM;
        short4v z4 = {0, 0, 0, 0};
        short8  z8 = {0, 0, 0, 0, 0, 0, 0, 0};
        *(short4v*)(op) = z4;
        *(short8*)(op + 4) = z8;
    }
}

// ---------------- host launch ----------------
extern "C" void kernel_launch(void* const* d_in, const int* in_sizes, int n_in,
                              void* d_out, int out_size, void* d_ws, size_t ws_size,
                              hipStream_t stream) {
    const float* x    = (const float*)d_in[0];
    const float* n1w  = (const float*)d_in[1];
    const float* n1b  = (const float*)d_in[2];
    const float* qkvw = (const float*)d_in[3];
    const float* qkvb = (const float*)d_in[4];
    const float* tbl  = (const float*)d_in[5];
    const float* pw   = (const float*)d_in[6];
    const float* pb   = (const float*)d_in[7];
    const float* n2w  = (const float*)d_in[8];
    const float* n2b  = (const float*)d_in[9];
    const float* f1w  = (const float*)d_in[10];
    const float* f1b  = (const float*)d_in[11];
    const float* f2w  = (const float*)d_in[12];
    const float* f2b  = (const float*)d_in[13];

    auto al = [](size_t b) { return (b + 255) & ~(size_t)255; };
    char* base = (char*)d_ws;
    size_t off = 0;
    auto alloc = [&](size_t bytes) -> char* { char* p = base + off; off += al(bytes); return p; };

    bf16* wqp  = (bf16*)alloc((size_t)QKVW * CPAD * 2);
    bf16* wp   = (bf16*)alloc((size_t)192 * 192 * 2);
    bf16* wf1  = (bf16*)alloc((size_t)768 * 192 * 2);
    bf16* wf2  = (bf16*)alloc((size_t)192 * 768 * 2);
    float* bfr = (float*)alloc((size_t)6144 * 4 * 4);
    float* f1bp = (float*)alloc((size_t)HPAD * 4);
    float* qbp  = (float*)alloc((size_t)QKVW * 4);
    size_t woff = off;

    size_t r1_per = al((size_t)IMG_TOK * HPAD * 2);   // qkv[576] then h[768]
    size_t r2_per = al((size_t)IMG_TOK * CPAD * 2);   // xn -> o -> x2n
    size_t r3_per = al((size_t)IMG_TOK * C_DIM * 4);  // x1 f32
    size_t per_img = r1_per + r2_per + r3_per;
    int g = 8;
    while (g > 1 && woff + per_img * (size_t)g > ws_size) g >>= 1;
    int nchunks = 8 / g;
    long Mc = (long)IMG_TOK * g;
    int nm = (int)(Mc / 128);

    bf16*  R1 = (bf16*)(base + woff);
    bf16*  R2 = (bf16*)(base + woff + r1_per * g);
    float* R3 = (float*)(base + woff + (r1_per + r2_per) * g);

    prep_wqkv<<<(QKVW * CPAD + 255) / 256, 256, 0, stream>>>(qkvw, wqp);
    prep_bqkv<<<(QKVW + 255) / 256, 256, 0, stream>>>(qkvb, qbp);
    prep_w<<<(192 * 192 + 255) / 256, 256, 0, stream>>>(pw, wp, 180, 180, 192, 192);
    prep_w<<<(768 * 192 + 255) / 256, 256, 0, stream>>>(f1w, wf1, 180, 720, 192, 768);
    prep_w<<<(192 * 768 + 255) / 256, 256, 0, stream>>>(f2w, wf2, 720, 180, 768, 192);
    prep_bias<<<(6144 + 255) / 256, 256, 0, stream>>>(tbl, bfr);
    prep_f1b<<<(HPAD + 255) / 256, 256, 0, stream>>>(f1b, f1bp);

    for (int ci = 0; ci < nchunks; ++ci) {
        const float* xc   = x + (size_t)ci * Mc * C_DIM;
        float*       outc = (float*)d_out + (size_t)ci * Mc * C_DIM;

        // 1. LN1 -> R2 (xn)
        ln_kernel<<<Mc / 4, 256, 0, stream>>>(xc, n1w, n1b, R2, (int)Mc);
        // 2. QKV -> R1 [Mc][576], P=9 x 64-wide
        mfma_gemm<<<dim3(nm * 9), 256, 0, stream>>>(
            R2, CPAD, wqp, qbp, R1, QKVW, QKVW, CPAD, 9);
        // 3. attention -> R2 (o)
        attn_mfma<<<dim3(256 * g), 384, 0, stream>>>(R1, bfr, R2);
        // 4. proj + residual(x) -> R3 (x1 f32) + fused LN2 -> R2 (x2n)
        mfma_gemm192<1><<<dim3(nm), 512, 0, stream>>>(
            R2, CPAD, wp, pb, xc, 180, R3, 180, 180, CPAD, n2w, n2b, R2);
        // 5. FC1 + sigmoid-GELU -> R1 (h), P=6 x 128-wide
        mfma_gemm128<1><<<dim3(nm * 6), 512, 0, stream>>>(
            R2, CPAD, wf1, f1bp, R1, HPAD, CPAD, 6);
        // 6. FC2 + residual(x1 f32) -> out (f32), single 192-panel
        mfma_gemm192<0><<<dim3(nm), 512, 0, stream>>>(
            R1, HPAD, wf2, f2b, R3, 180, outc, 180, 180, HPAD, nullptr, nullptr, nullptr);
    }
}

// Round 22
// 445.327 us; speedup vs baseline: 1.0665x; 1.0665x over previous
//
#include <hip/hip_runtime.h>
#include <hip/hip_bf16.h>

typedef __hip_bfloat16 bf16;
typedef __attribute__((ext_vector_type(8))) short short8;
typedef __attribute__((ext_vector_type(4))) short short4v;
typedef __attribute__((ext_vector_type(4))) float f32x4;

#define C_DIM 180
#define CPAD  192
#define NHEAD 6
#define HD    30
#define HID   720
#define HPAD  768
#define QKVW  576
#define LN_EPS 1e-5f
#define IMG_TOK 16384
#define QSCALE 0.18257418583505536f

static __device__ __forceinline__ bf16 f2bf(float f) { return __float2bfloat16(f); }
static __device__ __forceinline__ float bf2f(bf16 v) { return __bfloat162float(v); }
static __device__ __forceinline__ short bfbits(float f) {
    bf16 b = __float2bfloat16(f); return *reinterpret_cast<short*>(&b);
}
static __device__ __forceinline__ float gelu_sig(float v) {
    float e = __expf(-1.702f * v);
    return v * __builtin_amdgcn_rcpf(1.f + e);
}

// ---------------- weight prep ----------------
__global__ __launch_bounds__(256) void prep_w(const float* __restrict__ w, bf16* __restrict__ bt,
                                              int K, int N, int Kpad, int Npad) {
    int idx = blockIdx.x * 256 + threadIdx.x;
    if (idx >= Kpad * Npad) return;
    int k = idx % Kpad, n = idx / Kpad;
    float v = (k < K && n < N) ? w[(long)k * N + n] : 0.f;
    bt[idx] = f2bf(v);
}

__global__ __launch_bounds__(256) void prep_wqkv(const float* __restrict__ w, bf16* __restrict__ bt) {
    int idx = blockIdx.x * 256 + threadIdx.x;   // 576*192
    if (idx >= QKVW * CPAD) return;
    int k = idx % CPAD, c = idx / CPAD;
    int mat = c / 192, rem = c % 192;
    int hh = rem >> 5, dd = rem & 31;
    float v = 0.f;
    if (dd < HD && k < C_DIM) {
        v = w[(long)k * 540 + mat * 180 + hh * 30 + dd];
        if (mat == 0) v *= QSCALE;
    }
    bt[idx] = f2bf(v);
}
__global__ __launch_bounds__(256) void prep_bqkv(const float* __restrict__ b, float* __restrict__ bp) {
    int c = blockIdx.x * 256 + threadIdx.x;
    if (c >= QKVW) return;
    int mat = c / 192, rem = c % 192;
    int hh = rem >> 5, dd = rem & 31;
    float v = 0.f;
    if (dd < HD) {
        v = b[mat * 180 + hh * 30 + dd];
        if (mat == 0) v *= QSCALE;
    }
    bp[c] = v;
}

__global__ __launch_bounds__(256) void prep_f1b(const float* __restrict__ b, float* __restrict__ bp) {
    int i = blockIdx.x * 256 + threadIdx.x;
    if (i < HPAD) bp[i] = (i < HID) ? b[i] : 0.f;
}

__global__ __launch_bounds__(256) void prep_bias(const float* __restrict__ tbl,
                                                 float* __restrict__ bias_frag) {
    int idx = blockIdx.x * 256 + threadIdx.x;   // 6144
    if (idx >= 6144) return;
    int lane = idx & 63;
    int fj = (idx >> 6) & 3;
    int fi = (idx >> 8) & 3;
    int h  = idx >> 10;
    int g = lane >> 4, l15 = lane & 15;
    int kk = fj * 16 + l15;
    int rk = kk >> 3, ck = kk & 7;
    #pragma unroll
    for (int r = 0; r < 4; ++r) {
        int q = fi * 16 + g * 4 + r;
        int rq = q >> 3, cq = q & 7;
        int bidx = (rq - rk + 7) * 15 + (cq - ck + 7);
        bias_frag[idx * 4 + r] = tbl[bidx * NHEAD + h];
    }
}

// ---------------- LayerNorm ----------------
__global__ __launch_bounds__(256) void ln_kernel(const float* __restrict__ x,
                                                 const float* __restrict__ w,
                                                 const float* __restrict__ b,
                                                 bf16* __restrict__ out, int M) {
    int wave = threadIdx.x >> 6;
    int lane = threadIdx.x & 63;
    long row = (long)blockIdx.x * 4 + wave;
    if (row >= M) return;
    const float* xr = x + row * C_DIM;
    float e0 = xr[lane];
    float e1 = xr[lane + 64];
    float e2 = (lane < C_DIM - 128) ? xr[lane + 128] : 0.f;
    float s  = e0 + e1 + e2;
    float ss = e0*e0 + e1*e1 + e2*e2;
    #pragma unroll
    for (int off = 32; off > 0; off >>= 1) {
        s  += __shfl_xor(s,  off);
        ss += __shfl_xor(ss, off);
    }
    float mean = s * (1.f / C_DIM);
    float var  = ss * (1.f / C_DIM) - mean * mean;
    float rs   = rsqrtf(var + LN_EPS);
    bf16* orow = out + row * CPAD;
    orow[lane]      = f2bf((e0 - mean) * rs * w[lane]      + b[lane]);
    orow[lane + 64] = f2bf((e1 - mean) * rs * w[lane + 64] + b[lane + 64]);
    if (lane < C_DIM - 128)
        orow[lane + 128] = f2bf((e2 - mean) * rs * w[lane + 128] + b[lane + 128]);
    if (lane < CPAD - C_DIM)
        orow[C_DIM + lane] = f2bf(0.f);
}

#define GLL16(gp, lp) \
    __builtin_amdgcn_global_load_lds((const __attribute__((address_space(1))) unsigned int*)(gp), \
                                     (__attribute__((address_space(3))) unsigned int*)(lp), 16, 0, 0)

// ---------------- MFMA GEMM, 128x64 tile (QKV) ----------------
__global__ __launch_bounds__(256) void mfma_gemm(
    const bf16* __restrict__ A, int lda,
    const bf16* __restrict__ Bt,
    const float* __restrict__ bias,
    bf16* __restrict__ out, int ldo, int nstore,
    int Kpad, int P)
{
    __shared__ __align__(16) short smem[128 * 64 + 64 * 64];
    short* As = smem;
    short* Bs = smem + 128 * 64;
    int tid  = threadIdx.x;
    int lane = tid & 63;
    int wave = tid >> 6;
    int wm = wave >> 1, wn = wave & 1;
    int g4 = lane >> 4, l15 = lane & 15;

    int flat = blockIdx.x;
    int grp  = flat / (8 * P);
    int rem  = flat - grp * 8 * P;
    int p    = rem >> 3;
    long m0  = (long)(grp * 8 + (rem & 7)) * 128;
    int  n0  = p * 64;

    f32x4 acc[4][2] = {};

    int nkt = Kpad >> 6;
    for (int kt = 0; kt < nkt; ++kt) {
        int k0 = kt << 6;
        #pragma unroll
        for (int i = 0; i < 4; ++i) {
            int f = i * 256 + tid;
            int r = f >> 3, c = f & 7;
            const bf16* gp = A + (m0 + r) * (long)lda + k0 + ((c ^ (r & 7)) << 3);
            GLL16(gp, &As[(i * 256 + (wave << 6)) * 8]);
        }
        #pragma unroll
        for (int i = 0; i < 2; ++i) {
            int f = i * 256 + tid;
            int r = f >> 3, c = f & 7;
            const bf16* gp = Bt + (n0 + r) * (long)Kpad + k0 + ((c ^ (r & 7)) << 3);
            GLL16(gp, &Bs[(i * 256 + (wave << 6)) * 8]);
        }
        __syncthreads();
        #pragma unroll
        for (int ks = 0; ks < 2; ++ks) {
            short8 af[4], bfr[2];
            #pragma unroll
            for (int fi = 0; fi < 4; ++fi) {
                int r  = wm * 64 + fi * 16 + l15;
                int ch = ks * 4 + g4;
                af[fi] = *(const short8*)&As[r * 64 + ((ch ^ (r & 7)) << 3)];
            }
            #pragma unroll
            for (int fj = 0; fj < 2; ++fj) {
                int r  = wn * 32 + fj * 16 + l15;
                int ch = ks * 4 + g4;
                bfr[fj] = *(const short8*)&Bs[r * 64 + ((ch ^ (r & 7)) << 3)];
            }
            #pragma unroll
            for (int fi = 0; fi < 4; ++fi)
                #pragma unroll
                for (int fj = 0; fj < 2; ++fj)
                    acc[fi][fj] = __builtin_amdgcn_mfma_f32_16x16x32_bf16(af[fi], bfr[fj], acc[fi][fj], 0, 0, 0);
        }
        __syncthreads();
    }

    short* Cs = smem;
    #pragma unroll
    for (int fi = 0; fi < 4; ++fi)
        #pragma unroll
        for (int fj = 0; fj < 2; ++fj) {
            int col = wn * 32 + fj * 16 + l15;
            float bv = (n0 + col < nstore) ? bias[n0 + col] : 0.f;
            #pragma unroll
            for (int rg = 0; rg < 4; ++rg) {
                int row = wm * 64 + fi * 16 + g4 * 4 + rg;
                Cs[row * 72 + col] = bfbits(acc[fi][fj][rg] + bv);
            }
        }
    __syncthreads();
    #pragma unroll
    for (int i = 0; i < 4; ++i) {
        int t = i * 256 + tid;
        int row = t >> 3, c8 = t & 7;
        short8 v = *(const short8*)&Cs[row * 72 + c8 * 8];
        *(short8*)(out + (m0 + row) * (long)ldo + n0 + c8 * 8) = v;
    }
}

// ---------------- MFMA GEMM, 128x192 single-panel, 512 threads (proj / FC2) ----------------
// 8 waves (4m x 2n), wave tile 32x96, acc[2][6]. f32 out + optional f32 resid.
__global__ __launch_bounds__(512) void mfma_gemm192(
    const bf16* __restrict__ A, int lda,
    const bf16* __restrict__ Bt,            // [192][Kpad]
    const float* __restrict__ bias,
    const float* __restrict__ resid, int nres,
    float* __restrict__ out, int ldo, int nstore,
    int Kpad)
{
    __shared__ __align__(16) short smem[128 * 64 + 192 * 64];   // 16 + 24 = 40 KB
    short* As = smem;
    short* Bs = smem + 128 * 64;
    int tid  = threadIdx.x;
    int lane = tid & 63;
    int wave = tid >> 6;
    int wm = wave >> 1, wn = wave & 1;      // wm 0..3, wn 0..1
    int g4 = lane >> 4, l15 = lane & 15;

    int flat = blockIdx.x;                  // P=1: m-block = flat
    long m0  = (long)flat * 128;

    f32x4 acc[2][6] = {};

    int nkt = Kpad >> 6;
    for (int kt = 0; kt < nkt; ++kt) {
        int k0 = kt << 6;
        #pragma unroll
        for (int i = 0; i < 2; ++i) {       // A: 1024 chunks
            int f = i * 512 + tid;
            int r = f >> 3, c = f & 7;
            const bf16* gp = A + (m0 + r) * (long)lda + k0 + ((c ^ (r & 7)) << 3);
            GLL16(gp, &As[(i * 512 + (wave << 6)) * 8]);
        }
        #pragma unroll
        for (int i = 0; i < 3; ++i) {       // B: 192 rows x 8 = 1536 chunks
            int f = i * 512 + tid;
            int r = f >> 3, c = f & 7;
            const bf16* gp = Bt + r * (long)Kpad + k0 + ((c ^ (r & 7)) << 3);
            GLL16(gp, &Bs[(i * 512 + (wave << 6)) * 8]);
        }
        __syncthreads();
        #pragma unroll
        for (int ks = 0; ks < 2; ++ks) {
            short8 af[2], bfr[6];
            #pragma unroll
            for (int fi = 0; fi < 2; ++fi) {
                int r  = wm * 32 + fi * 16 + l15;
                int ch = ks * 4 + g4;
                af[fi] = *(const short8*)&As[r * 64 + ((ch ^ (r & 7)) << 3)];
            }
            #pragma unroll
            for (int fj = 0; fj < 6; ++fj) {
                int r  = wn * 96 + fj * 16 + l15;
                int ch = ks * 4 + g4;
                bfr[fj] = *(const short8*)&Bs[r * 64 + ((ch ^ (r & 7)) << 3)];
            }
            #pragma unroll
            for (int fi = 0; fi < 2; ++fi)
                #pragma unroll
                for (int fj = 0; fj < 6; ++fj)
                    acc[fi][fj] = __builtin_amdgcn_mfma_f32_16x16x32_bf16(af[fi], bfr[fj], acc[fi][fj], 0, 0, 0);
        }
        __syncthreads();
    }

    // epilogue: 4 phases of 32 rows via f32 LDS [32][196], coalesced stores + resid
    float* Cf = (float*)smem;
    int cpr = nstore >> 2;                  // 45 float4 chunks per row
    #pragma unroll
    for (int ph = 0; ph < 4; ++ph) {
        if (wm == ph) {
            #pragma unroll
            for (int fi = 0; fi < 2; ++fi)
                #pragma unroll
                for (int fj = 0; fj < 6; ++fj) {
                    int col = wn * 96 + fj * 16 + l15;
                    float bv = (col < nstore) ? bias[col] : 0.f;
                    #pragma unroll
                    for (int rg = 0; rg < 4; ++rg) {
                        int lrow = fi * 16 + g4 * 4 + rg;
                        Cf[lrow * 196 + col] = acc[fi][fj][rg] + bv;
                    }
                }
        }
        __syncthreads();
        for (int t = tid; t < 32 * cpr; t += 512) {
            int row = t / cpr, cc = (t - row * cpr) * 4;
            long grow = m0 + ph * 32 + row;
            f32x4 v = *(const f32x4*)&Cf[row * 196 + cc];
            if (resid) {
                f32x4 rv = *(const f32x4*)(resid + grow * (long)nres + cc);
                v += rv;
            }
            *(f32x4*)(out + grow * (long)ldo + cc) = v;
        }
        __syncthreads();
    }
}

// ---------------- MFMA GEMM, 128x128 tile, 512 threads (FC1) ----------------
template<int DO_GELU>
__global__ __launch_bounds__(512) void mfma_gemm128(
    const bf16* __restrict__ A, int lda,
    const bf16* __restrict__ Bt,
    const float* __restrict__ bias,
    bf16* __restrict__ out, int ldo,
    int Kpad, int P)
{
    __shared__ __align__(16) short smem[128 * 64 + 128 * 64];
    short* As = smem;
    short* Bs = smem + 128 * 64;
    int tid  = threadIdx.x;
    int lane = tid & 63;
    int wave = tid >> 6;
    int wm = wave >> 1, wn = wave & 1;
    int g4 = lane >> 4, l15 = lane & 15;

    int flat = blockIdx.x;
    int grp  = flat / (8 * P);
    int rem  = flat - grp * 8 * P;
    int p    = rem >> 3;
    long m0  = (long)(grp * 8 + (rem & 7)) * 128;
    int  n0  = p * 128;

    f32x4 acc[2][4] = {};

    int nkt = Kpad >> 6;
    for (int kt = 0; kt < nkt; ++kt) {
        int k0 = kt << 6;
        #pragma unroll
        for (int i = 0; i < 2; ++i) {
            int f = i * 512 + tid;
            int r = f >> 3, c = f & 7;
            const bf16* gp = A + (m0 + r) * (long)lda + k0 + ((c ^ (r & 7)) << 3);
            GLL16(gp, &As[(i * 512 + (wave << 6)) * 8]);
        }
        #pragma unroll
        for (int i = 0; i < 2; ++i) {
            int f = i * 512 + tid;
            int r = f >> 3, c = f & 7;
            const bf16* gp = Bt + (n0 + r) * (long)Kpad + k0 + ((c ^ (r & 7)) << 3);
            GLL16(gp, &Bs[(i * 512 + (wave << 6)) * 8]);
        }
        __syncthreads();
        #pragma unroll
        for (int ks = 0; ks < 2; ++ks) {
            short8 af[2], bfr[4];
            #pragma unroll
            for (int fi = 0; fi < 2; ++fi) {
                int r  = wm * 32 + fi * 16 + l15;
                int ch = ks * 4 + g4;
                af[fi] = *(const short8*)&As[r * 64 + ((ch ^ (r & 7)) << 3)];
            }
            #pragma unroll
            for (int fj = 0; fj < 4; ++fj) {
                int r  = wn * 64 + fj * 16 + l15;
                int ch = ks * 4 + g4;
                bfr[fj] = *(const short8*)&Bs[r * 64 + ((ch ^ (r & 7)) << 3)];
            }
            #pragma unroll
            for (int fi = 0; fi < 2; ++fi)
                #pragma unroll
                for (int fj = 0; fj < 4; ++fj)
                    acc[fi][fj] = __builtin_amdgcn_mfma_f32_16x16x32_bf16(af[fi], bfr[fj], acc[fi][fj], 0, 0, 0);
        }
        __syncthreads();
    }

    short* Cs = smem;
    #pragma unroll
    for (int fi = 0; fi < 2; ++fi)
        #pragma unroll
        for (int fj = 0; fj < 4; ++fj) {
            int col = wn * 64 + fj * 16 + l15;
            float bv = bias[n0 + col];
            #pragma unroll
            for (int rg = 0; rg < 4; ++rg) {
                int row = wm * 32 + fi * 16 + g4 * 4 + rg;
                float v = acc[fi][fj][rg] + bv;
                if (DO_GELU) v = gelu_sig(v);
                int ch = (col >> 3) ^ (row & 7);
                Cs[row * 128 + (ch << 3) + (col & 7)] = bfbits(v);
            }
        }
    __syncthreads();
    #pragma unroll
    for (int i = 0; i < 4; ++i) {
        int t = i * 512 + tid;
        int row = t >> 4, c16 = t & 15;
        short8 v = *(const short8*)&Cs[row * 128 + ((c16 ^ (row & 7)) << 3)];
        *(short8*)(out + (m0 + row) * (long)ldo + n0 + c16 * 8) = v;
    }
}

// ---------------- MFMA window attention ----------------
__global__ __launch_bounds__(384, 3) void attn_mfma(
    const bf16* __restrict__ qkv,
    const float* __restrict__ bias_frag,
    bf16* __restrict__ o)
{
    __shared__ __align__(16) short lds[6 * 4096];
    int tid  = threadIdx.x;
    int wave = tid >> 6;
    int lane = tid & 63;
    int h = wave;
    int w = blockIdx.x;
    int b = w >> 8, rem = w & 255;
    int wi = rem >> 4, wj = rem & 15;
    long base = (long)b * IMG_TOK + wi * 8 * 128 + wj * 8;
    int g = lane >> 4, l15 = lane & 15;

    short* Vt = &lds[wave * 4096];
    short* Ph = &lds[wave * 4096 + 2048];

    short8 qf[4], kf[4];
    #pragma unroll
    for (int fi = 0; fi < 4; ++fi) {
        int q = fi * 16 + l15;
        long t = base + (q >> 3) * 128 + (q & 7);
        const bf16* rowp = qkv + t * QKVW + h * 32 + g * 8;
        qf[fi] = *(const short8*)(rowp);
        kf[fi] = *(const short8*)(rowp + 192);
    }

    {
        int t = lane;
        const bf16* vp = qkv + (base + (t >> 3) * 128 + (t & 7)) * QKVW + 384 + h * 32;
        short8 v0 = *(const short8*)(vp);
        short8 v1 = *(const short8*)(vp + 8);
        short8 v2 = *(const short8*)(vp + 16);
        short8 v3 = *(const short8*)(vp + 24);
        int ct = t >> 3, t7 = t & 7;
        #pragma unroll
        for (int d = 0; d < 8; ++d)  Vt[d * 64 + ((ct ^ d) << 3) + t7] = v0[d];
        #pragma unroll
        for (int d = 8; d < 16; ++d) Vt[d * 64 + ((ct ^ (d & 7)) << 3) + t7] = v1[d - 8];
        #pragma unroll
        for (int d = 16; d < 24; ++d) Vt[d * 64 + ((ct ^ (d & 7)) << 3) + t7] = v2[d - 16];
        #pragma unroll
        for (int d = 24; d < 32; ++d) Vt[d * 64 + ((ct ^ (d & 7)) << 3) + t7] = v3[d - 24];
    }

    f32x4 S[4][4];
    #pragma unroll
    for (int fi = 0; fi < 4; ++fi)
        #pragma unroll
        for (int fj = 0; fj < 4; ++fj)
            S[fi][fj] = *(const f32x4*)(bias_frag + (((h * 4 + fi) * 4 + fj) * 64 + lane) * 4);
    #pragma unroll
    for (int fi = 0; fi < 4; ++fi)
        #pragma unroll
        for (int fj = 0; fj < 4; ++fj)
            S[fi][fj] = __builtin_amdgcn_mfma_f32_16x16x32_bf16(qf[fi], kf[fj], S[fi][fj], 0, 0, 0);

    f32x4 mrow[4], lsum[4];
    #pragma unroll
    for (int fi = 0; fi < 4; ++fi) {
        f32x4 a = S[fi][0], c = S[fi][2];
        #pragma unroll
        for (int cc = 0; cc < 4; ++cc) {
            a[cc] = fmaxf(a[cc], S[fi][1][cc]);
            c[cc] = fmaxf(c[cc], S[fi][3][cc]);
            a[cc] = fmaxf(a[cc], c[cc]);
        }
        mrow[fi] = a;
    }
    #pragma unroll
    for (int mask = 1; mask <= 8; mask <<= 1)
        #pragma unroll
        for (int fi = 0; fi < 4; ++fi)
            #pragma unroll
            for (int cc = 0; cc < 4; ++cc)
                mrow[fi][cc] = fmaxf(mrow[fi][cc], __shfl_xor(mrow[fi][cc], mask));
    #pragma unroll
    for (int fi = 0; fi < 4; ++fi)
        #pragma unroll
        for (int fj = 0; fj < 4; ++fj)
            #pragma unroll
            for (int cc = 0; cc < 4; ++cc)
                S[fi][fj][cc] = __expf(S[fi][fj][cc] - mrow[fi][cc]);
    #pragma unroll
    for (int fi = 0; fi < 4; ++fi) {
        f32x4 a = S[fi][0] + S[fi][1];
        f32x4 c = S[fi][2] + S[fi][3];
        lsum[fi] = a + c;
    }
    #pragma unroll
    for (int mask = 1; mask <= 8; mask <<= 1)
        #pragma unroll
        for (int fi = 0; fi < 4; ++fi)
            #pragma unroll
            for (int cc = 0; cc < 4; ++cc)
                lsum[fi][cc] += __shfl_xor(lsum[fi][cc], mask);

    f32x4 O[4][2] = {};
    #pragma unroll
    for (int ks = 0; ks < 2; ++ks) {
        #pragma unroll
        for (int fi = 0; fi < 4; ++fi)
            #pragma unroll
            for (int f2 = 0; f2 < 2; ++f2) {
                int fj = ks * 2 + f2;
                int kh = f2 * 16 + l15;
                #pragma unroll
                for (int r = 0; r < 4; ++r) {
                    int q = fi * 16 + g * 4 + r;
                    int c = (kh >> 3) ^ r ^ g;
                    Ph[q * 32 + (c << 3) + (kh & 7)] = bfbits(S[fi][fj][r]);
                }
            }
        short8 vf[2];
        #pragma unroll
        for (int f2 = 0; f2 < 2; ++f2) {
            int d = f2 * 16 + l15;
            int cv = (ks * 4 + g) ^ (d & 7);
            vf[f2] = *(const short8*)&Vt[d * 64 + (cv << 3)];
        }
        #pragma unroll
        for (int fi = 0; fi < 4; ++fi) {
            int q = fi * 16 + l15;
            int cr = g ^ (q & 3) ^ ((q >> 2) & 3);
            short8 pf = *(const short8*)&Ph[q * 32 + (cr << 3)];
            #pragma unroll
            for (int f2 = 0; f2 < 2; ++f2)
                O[fi][f2] = __builtin_amdgcn_mfma_f32_16x16x32_bf16(pf, vf[f2], O[fi][f2], 0, 0, 0);
        }
    }

    #pragma unroll
    for (int fi = 0; fi < 4; ++fi) {
        f32x4 inv;
        #pragma unroll
        for (int cc = 0; cc < 4; ++cc) inv[cc] = 1.f / lsum[fi][cc];
        #pragma unroll
        for (int r = 0; r < 4; ++r) {
            int q = fi * 16 + g * 4 + r;
            long t = base + (q >> 3) * 128 + (q & 7);
            bf16* op = o + t * CPAD + h * HD;
            op[l15] = f2bf(O[fi][0][r] * inv[r]);
            if (l15 < HD - 16)
                op[16 + l15] = f2bf(O[fi][1][r] * inv[r]);
        }
    }
    if (h == 0) {
        long t = base + (lane >> 3) * 128 + (lane & 7);
        bf16* op = o + t * CPAD + C_DIM;
        short4v z4 = {0, 0, 0, 0};
        short8  z8 = {0, 0, 0, 0, 0, 0, 0, 0};
        *(short4v*)(op) = z4;
        *(short8*)(op + 4) = z8;
    }
}

// ---------------- host launch ----------------
extern "C" void kernel_launch(void* const* d_in, const int* in_sizes, int n_in,
                              void* d_out, int out_size, void* d_ws, size_t ws_size,
                              hipStream_t stream) {
    const float* x    = (const float*)d_in[0];
    const float* n1w  = (const float*)d_in[1];
    const float* n1b  = (const float*)d_in[2];
    const float* qkvw = (const float*)d_in[3];
    const float* qkvb = (const float*)d_in[4];
    const float* tbl  = (const float*)d_in[5];
    const float* pw   = (const float*)d_in[6];
    const float* pb   = (const float*)d_in[7];
    const float* n2w  = (const float*)d_in[8];
    const float* n2b  = (const float*)d_in[9];
    const float* f1w  = (const float*)d_in[10];
    const float* f1b  = (const float*)d_in[11];
    const float* f2w  = (const float*)d_in[12];
    const float* f2b  = (const float*)d_in[13];

    auto al = [](size_t b) { return (b + 255) & ~(size_t)255; };
    char* base = (char*)d_ws;
    size_t off = 0;
    auto alloc = [&](size_t bytes) -> char* { char* p = base + off; off += al(bytes); return p; };

    bf16* wqp  = (bf16*)alloc((size_t)QKVW * CPAD * 2);
    bf16* wp   = (bf16*)alloc((size_t)192 * 192 * 2);
    bf16* wf1  = (bf16*)alloc((size_t)768 * 192 * 2);
    bf16* wf2  = (bf16*)alloc((size_t)192 * 768 * 2);
    float* bfr = (float*)alloc((size_t)6144 * 4 * 4);
    float* f1bp = (float*)alloc((size_t)HPAD * 4);
    float* qbp  = (float*)alloc((size_t)QKVW * 4);
    size_t woff = off;

    size_t r1_per = al((size_t)IMG_TOK * HPAD * 2);   // qkv[576] then h[768]
    size_t r2_per = al((size_t)IMG_TOK * CPAD * 2);   // xn -> o -> x2n
    size_t r3_per = al((size_t)IMG_TOK * C_DIM * 4);  // x1 f32
    size_t per_img = r1_per + r2_per + r3_per;
    int g = 8;
    while (g > 1 && woff + per_img * (size_t)g > ws_size) g >>= 1;
    int nchunks = 8 / g;
    long Mc = (long)IMG_TOK * g;
    int nm = (int)(Mc / 128);

    bf16*  R1 = (bf16*)(base + woff);
    bf16*  R2 = (bf16*)(base + woff + r1_per * g);
    float* R3 = (float*)(base + woff + (r1_per + r2_per) * g);

    prep_wqkv<<<(QKVW * CPAD + 255) / 256, 256, 0, stream>>>(qkvw, wqp);
    prep_bqkv<<<(QKVW + 255) / 256, 256, 0, stream>>>(qkvb, qbp);
    prep_w<<<(192 * 192 + 255) / 256, 256, 0, stream>>>(pw, wp, 180, 180, 192, 192);
    prep_w<<<(768 * 192 + 255) / 256, 256, 0, stream>>>(f1w, wf1, 180, 720, 192, 768);
    prep_w<<<(192 * 768 + 255) / 256, 256, 0, stream>>>(f2w, wf2, 720, 180, 768, 192);
    prep_bias<<<(6144 + 255) / 256, 256, 0, stream>>>(tbl, bfr);
    prep_f1b<<<(HPAD + 255) / 256, 256, 0, stream>>>(f1b, f1bp);

    for (int ci = 0; ci < nchunks; ++ci) {
        const float* xc   = x + (size_t)ci * Mc * C_DIM;
        float*       outc = (float*)d_out + (size_t)ci * Mc * C_DIM;

        // 1. LN1 -> R2 (xn)
        ln_kernel<<<Mc / 4, 256, 0, stream>>>(xc, n1w, n1b, R2, (int)Mc);
        // 2. QKV -> R1 [Mc][576], P=9 x 64-wide
        mfma_gemm<<<dim3(nm * 9), 256, 0, stream>>>(
            R2, CPAD, wqp, qbp, R1, QKVW, QKVW, CPAD, 9);
        // 3. attention -> R2 (o)
        attn_mfma<<<dim3(256 * g), 384, 0, stream>>>(R1, bfr, R2);
        // 4. proj + residual(x f32) -> R3 (x1 f32), single 192-panel
        mfma_gemm192<<<dim3(nm), 512, 0, stream>>>(
            R2, CPAD, wp, pb, xc, 180, R3, 180, 180, CPAD);
        // 5. LN2 -> R2 (x2n)
        ln_kernel<<<Mc / 4, 256, 0, stream>>>(R3, n2w, n2b, R2, (int)Mc);
        // 6. FC1 + sigmoid-GELU -> R1 (h), P=6 x 128-wide
        mfma_gemm128<1><<<dim3(nm * 6), 512, 0, stream>>>(
            R2, CPAD, wf1, f1bp, R1, HPAD, CPAD, 6);
        // 7. FC2 + residual(x1 f32) -> out (f32), single 192-panel
        mfma_gemm192<<<dim3(nm), 512, 0, stream>>>(
            R1, HPAD, wf2, f2b, R3, 180, outc, 180, 180, HPAD);
    }
}

// Round 23
// 441.013 us; speedup vs baseline: 1.0769x; 1.0098x over previous
//
#include <hip/hip_runtime.h>
#include <hip/hip_bf16.h>

typedef __hip_bfloat16 bf16;
typedef __attribute__((ext_vector_type(8))) short short8;
typedef __attribute__((ext_vector_type(4))) short short4v;
typedef __attribute__((ext_vector_type(4))) float f32x4;

#define C_DIM 180
#define CPAD  192
#define NHEAD 6
#define HD    30
#define HID   720
#define HPAD  768
#define QKVW  576
#define LN_EPS 1e-5f
#define IMG_TOK 16384
#define QSCALE 0.18257418583505536f

static __device__ __forceinline__ bf16 f2bf(float f) { return __float2bfloat16(f); }
static __device__ __forceinline__ float bf2f(bf16 v) { return __bfloat162float(v); }
static __device__ __forceinline__ short bfbits(float f) {
    bf16 b = __float2bfloat16(f); return *reinterpret_cast<short*>(&b);
}
static __device__ __forceinline__ float gelu_sig(float v) {
    float e = __expf(-1.702f * v);
    return v * __builtin_amdgcn_rcpf(1.f + e);
}

// ---------------- weight prep ----------------
__global__ __launch_bounds__(256) void prep_w(const float* __restrict__ w, bf16* __restrict__ bt,
                                              int K, int N, int Kpad, int Npad) {
    int idx = blockIdx.x * 256 + threadIdx.x;
    if (idx >= Kpad * Npad) return;
    int k = idx % Kpad, n = idx / Kpad;
    float v = (k < K && n < N) ? w[(long)k * N + n] : 0.f;
    bt[idx] = f2bf(v);
}

__global__ __launch_bounds__(256) void prep_wqkv(const float* __restrict__ w, bf16* __restrict__ bt) {
    int idx = blockIdx.x * 256 + threadIdx.x;   // 576*192
    if (idx >= QKVW * CPAD) return;
    int k = idx % CPAD, c = idx / CPAD;
    int mat = c / 192, rem = c % 192;
    int hh = rem >> 5, dd = rem & 31;
    float v = 0.f;
    if (dd < HD && k < C_DIM) {
        v = w[(long)k * 540 + mat * 180 + hh * 30 + dd];
        if (mat == 0) v *= QSCALE;
    }
    bt[idx] = f2bf(v);
}
__global__ __launch_bounds__(256) void prep_bqkv(const float* __restrict__ b, float* __restrict__ bp) {
    int c = blockIdx.x * 256 + threadIdx.x;
    if (c >= QKVW) return;
    int mat = c / 192, rem = c % 192;
    int hh = rem >> 5, dd = rem & 31;
    float v = 0.f;
    if (dd < HD) {
        v = b[mat * 180 + hh * 30 + dd];
        if (mat == 0) v *= QSCALE;
    }
    bp[c] = v;
}

__global__ __launch_bounds__(256) void prep_f1b(const float* __restrict__ b, float* __restrict__ bp) {
    int i = blockIdx.x * 256 + threadIdx.x;
    if (i < HPAD) bp[i] = (i < HID) ? b[i] : 0.f;
}

__global__ __launch_bounds__(256) void prep_bias(const float* __restrict__ tbl,
                                                 float* __restrict__ bias_frag) {
    int idx = blockIdx.x * 256 + threadIdx.x;   // 6144
    if (idx >= 6144) return;
    int lane = idx & 63;
    int fj = (idx >> 6) & 3;
    int fi = (idx >> 8) & 3;
    int h  = idx >> 10;
    int g = lane >> 4, l15 = lane & 15;
    int kk = fj * 16 + l15;
    int rk = kk >> 3, ck = kk & 7;
    #pragma unroll
    for (int r = 0; r < 4; ++r) {
        int q = fi * 16 + g * 4 + r;
        int rq = q >> 3, cq = q & 7;
        int bidx = (rq - rk + 7) * 15 + (cq - ck + 7);
        bias_frag[idx * 4 + r] = tbl[bidx * NHEAD + h];
    }
}

// ---------------- LayerNorm ----------------
__global__ __launch_bounds__(256) void ln_kernel(const float* __restrict__ x,
                                                 const float* __restrict__ w,
                                                 const float* __restrict__ b,
                                                 bf16* __restrict__ out, int M) {
    int wave = threadIdx.x >> 6;
    int lane = threadIdx.x & 63;
    long row = (long)blockIdx.x * 4 + wave;
    if (row >= M) return;
    const float* xr = x + row * C_DIM;
    float e0 = xr[lane];
    float e1 = xr[lane + 64];
    float e2 = (lane < C_DIM - 128) ? xr[lane + 128] : 0.f;
    float s  = e0 + e1 + e2;
    float ss = e0*e0 + e1*e1 + e2*e2;
    #pragma unroll
    for (int off = 32; off > 0; off >>= 1) {
        s  += __shfl_xor(s,  off);
        ss += __shfl_xor(ss, off);
    }
    float mean = s * (1.f / C_DIM);
    float var  = ss * (1.f / C_DIM) - mean * mean;
    float rs   = rsqrtf(var + LN_EPS);
    bf16* orow = out + row * CPAD;
    orow[lane]      = f2bf((e0 - mean) * rs * w[lane]      + b[lane]);
    orow[lane + 64] = f2bf((e1 - mean) * rs * w[lane + 64] + b[lane + 64]);
    if (lane < C_DIM - 128)
        orow[lane + 128] = f2bf((e2 - mean) * rs * w[lane + 128] + b[lane + 128]);
    if (lane < CPAD - C_DIM)
        orow[C_DIM + lane] = f2bf(0.f);
}

#define GLL16(gp, lp) \
    __builtin_amdgcn_global_load_lds((const __attribute__((address_space(1))) unsigned int*)(gp), \
                                     (__attribute__((address_space(3))) unsigned int*)(lp), 16, 0, 0)

// ---------------- MFMA GEMM, 128x192 panel, 512 threads, bf16 out (QKV) ----------------
// 8 waves (4m x 2n), wave tile 32x96, acc[2][6]. XCD-chunked over P panels of 192.
__global__ __launch_bounds__(512) void mfma_gemm192b(
    const bf16* __restrict__ A, int lda,
    const bf16* __restrict__ Bt,            // [Npad][Kpad]
    const float* __restrict__ bias,
    bf16* __restrict__ out, int ldo,
    int Kpad, int P)
{
    __shared__ __align__(16) short smem[128 * 64 + 192 * 64];   // 40 KB; epilogue reuses
    short* As = smem;
    short* Bs = smem + 128 * 64;
    int tid  = threadIdx.x;
    int lane = tid & 63;
    int wave = tid >> 6;
    int wm = wave >> 1, wn = wave & 1;      // wm 0..3, wn 0..1
    int g4 = lane >> 4, l15 = lane & 15;

    int flat = blockIdx.x;
    int grp  = flat / (8 * P);
    int rem  = flat - grp * 8 * P;
    int p    = rem >> 3;
    long m0  = (long)(grp * 8 + (rem & 7)) * 128;
    int  n0  = p * 192;

    f32x4 acc[2][6] = {};

    int nkt = Kpad >> 6;
    for (int kt = 0; kt < nkt; ++kt) {
        int k0 = kt << 6;
        #pragma unroll
        for (int i = 0; i < 2; ++i) {       // A: 1024 chunks
            int f = i * 512 + tid;
            int r = f >> 3, c = f & 7;
            const bf16* gp = A + (m0 + r) * (long)lda + k0 + ((c ^ (r & 7)) << 3);
            GLL16(gp, &As[(i * 512 + (wave << 6)) * 8]);
        }
        #pragma unroll
        for (int i = 0; i < 3; ++i) {       // B: 192 rows x 8 = 1536 chunks
            int f = i * 512 + tid;
            int r = f >> 3, c = f & 7;
            const bf16* gp = Bt + (n0 + r) * (long)Kpad + k0 + ((c ^ (r & 7)) << 3);
            GLL16(gp, &Bs[(i * 512 + (wave << 6)) * 8]);
        }
        __syncthreads();
        #pragma unroll
        for (int ks = 0; ks < 2; ++ks) {
            short8 af[2], bfr[6];
            #pragma unroll
            for (int fi = 0; fi < 2; ++fi) {
                int r  = wm * 32 + fi * 16 + l15;
                int ch = ks * 4 + g4;
                af[fi] = *(const short8*)&As[r * 64 + ((ch ^ (r & 7)) << 3)];
            }
            #pragma unroll
            for (int fj = 0; fj < 6; ++fj) {
                int r  = wn * 96 + fj * 16 + l15;
                int ch = ks * 4 + g4;
                bfr[fj] = *(const short8*)&Bs[r * 64 + ((ch ^ (r & 7)) << 3)];
            }
            #pragma unroll
            for (int fi = 0; fi < 2; ++fi)
                #pragma unroll
                for (int fj = 0; fj < 6; ++fj)
                    acc[fi][fj] = __builtin_amdgcn_mfma_f32_16x16x32_bf16(af[fi], bfr[fj], acc[fi][fj], 0, 0, 0);
        }
        __syncthreads();
    }

    // epilogue: two 64-row phases via bf16 LDS [64][200], coalesced 16B copies
    short* Cs = smem;
    #pragma unroll
    for (int ph = 0; ph < 2; ++ph) {
        if ((wm >> 1) == ph) {
            int lbase = (wm & 1) * 32;
            #pragma unroll
            for (int fi = 0; fi < 2; ++fi)
                #pragma unroll
                for (int fj = 0; fj < 6; ++fj) {
                    int col = wn * 96 + fj * 16 + l15;
                    float bv = bias[n0 + col];
                    #pragma unroll
                    for (int rg = 0; rg < 4; ++rg) {
                        int lrow = lbase + fi * 16 + g4 * 4 + rg;
                        Cs[lrow * 200 + col] = bfbits(acc[fi][fj][rg] + bv);
                    }
                }
        }
        __syncthreads();
        #pragma unroll
        for (int i = 0; i < 3; ++i) {
            int t = i * 512 + tid;          // 1536 chunks = 64 rows x 24
            int row = t / 24, c8 = t - row * 24;
            short8 v = *(const short8*)&Cs[row * 200 + c8 * 8];
            *(short8*)(out + (m0 + ph * 64 + row) * (long)ldo + n0 + c8 * 8) = v;
        }
        __syncthreads();
    }
}

// ---------------- MFMA GEMM, 128x192 single-panel, 512 threads, f32 out (proj / FC2) ----------------
__global__ __launch_bounds__(512) void mfma_gemm192(
    const bf16* __restrict__ A, int lda,
    const bf16* __restrict__ Bt,            // [192][Kpad]
    const float* __restrict__ bias,
    const float* __restrict__ resid, int nres,
    float* __restrict__ out, int ldo, int nstore,
    int Kpad)
{
    __shared__ __align__(16) short smem[128 * 64 + 192 * 64];   // 40 KB
    short* As = smem;
    short* Bs = smem + 128 * 64;
    int tid  = threadIdx.x;
    int lane = tid & 63;
    int wave = tid >> 6;
    int wm = wave >> 1, wn = wave & 1;
    int g4 = lane >> 4, l15 = lane & 15;

    int flat = blockIdx.x;
    long m0  = (long)flat * 128;

    f32x4 acc[2][6] = {};

    int nkt = Kpad >> 6;
    for (int kt = 0; kt < nkt; ++kt) {
        int k0 = kt << 6;
        #pragma unroll
        for (int i = 0; i < 2; ++i) {
            int f = i * 512 + tid;
            int r = f >> 3, c = f & 7;
            const bf16* gp = A + (m0 + r) * (long)lda + k0 + ((c ^ (r & 7)) << 3);
            GLL16(gp, &As[(i * 512 + (wave << 6)) * 8]);
        }
        #pragma unroll
        for (int i = 0; i < 3; ++i) {
            int f = i * 512 + tid;
            int r = f >> 3, c = f & 7;
            const bf16* gp = Bt + r * (long)Kpad + k0 + ((c ^ (r & 7)) << 3);
            GLL16(gp, &Bs[(i * 512 + (wave << 6)) * 8]);
        }
        __syncthreads();
        #pragma unroll
        for (int ks = 0; ks < 2; ++ks) {
            short8 af[2], bfr[6];
            #pragma unroll
            for (int fi = 0; fi < 2; ++fi) {
                int r  = wm * 32 + fi * 16 + l15;
                int ch = ks * 4 + g4;
                af[fi] = *(const short8*)&As[r * 64 + ((ch ^ (r & 7)) << 3)];
            }
            #pragma unroll
            for (int fj = 0; fj < 6; ++fj) {
                int r  = wn * 96 + fj * 16 + l15;
                int ch = ks * 4 + g4;
                bfr[fj] = *(const short8*)&Bs[r * 64 + ((ch ^ (r & 7)) << 3)];
            }
            #pragma unroll
            for (int fi = 0; fi < 2; ++fi)
                #pragma unroll
                for (int fj = 0; fj < 6; ++fj)
                    acc[fi][fj] = __builtin_amdgcn_mfma_f32_16x16x32_bf16(af[fi], bfr[fj], acc[fi][fj], 0, 0, 0);
        }
        __syncthreads();
    }

    // epilogue: 4 phases of 32 rows via f32 LDS [32][196], coalesced stores + resid
    float* Cf = (float*)smem;
    int cpr = nstore >> 2;                  // 45 float4 chunks per row
    #pragma unroll
    for (int ph = 0; ph < 4; ++ph) {
        if (wm == ph) {
            #pragma unroll
            for (int fi = 0; fi < 2; ++fi)
                #pragma unroll
                for (int fj = 0; fj < 6; ++fj) {
                    int col = wn * 96 + fj * 16 + l15;
                    float bv = (col < nstore) ? bias[col] : 0.f;
                    #pragma unroll
                    for (int rg = 0; rg < 4; ++rg) {
                        int lrow = fi * 16 + g4 * 4 + rg;
                        Cf[lrow * 196 + col] = acc[fi][fj][rg] + bv;
                    }
                }
        }
        __syncthreads();
        for (int t = tid; t < 32 * cpr; t += 512) {
            int row = t / cpr, cc = (t - row * cpr) * 4;
            long grow = m0 + ph * 32 + row;
            f32x4 v = *(const f32x4*)&Cf[row * 196 + cc];
            if (resid) {
                f32x4 rv = *(const f32x4*)(resid + grow * (long)nres + cc);
                v += rv;
            }
            *(f32x4*)(out + grow * (long)ldo + cc) = v;
        }
        __syncthreads();
    }
}

// ---------------- MFMA GEMM, 128x128 tile, 512 threads (FC1) ----------------
template<int DO_GELU>
__global__ __launch_bounds__(512) void mfma_gemm128(
    const bf16* __restrict__ A, int lda,
    const bf16* __restrict__ Bt,
    const float* __restrict__ bias,
    bf16* __restrict__ out, int ldo,
    int Kpad, int P)
{
    __shared__ __align__(16) short smem[128 * 64 + 128 * 64];
    short* As = smem;
    short* Bs = smem + 128 * 64;
    int tid  = threadIdx.x;
    int lane = tid & 63;
    int wave = tid >> 6;
    int wm = wave >> 1, wn = wave & 1;
    int g4 = lane >> 4, l15 = lane & 15;

    int flat = blockIdx.x;
    int grp  = flat / (8 * P);
    int rem  = flat - grp * 8 * P;
    int p    = rem >> 3;
    long m0  = (long)(grp * 8 + (rem & 7)) * 128;
    int  n0  = p * 128;

    f32x4 acc[2][4] = {};

    int nkt = Kpad >> 6;
    for (int kt = 0; kt < nkt; ++kt) {
        int k0 = kt << 6;
        #pragma unroll
        for (int i = 0; i < 2; ++i) {
            int f = i * 512 + tid;
            int r = f >> 3, c = f & 7;
            const bf16* gp = A + (m0 + r) * (long)lda + k0 + ((c ^ (r & 7)) << 3);
            GLL16(gp, &As[(i * 512 + (wave << 6)) * 8]);
        }
        #pragma unroll
        for (int i = 0; i < 2; ++i) {
            int f = i * 512 + tid;
            int r = f >> 3, c = f & 7;
            const bf16* gp = Bt + (n0 + r) * (long)Kpad + k0 + ((c ^ (r & 7)) << 3);
            GLL16(gp, &Bs[(i * 512 + (wave << 6)) * 8]);
        }
        __syncthreads();
        #pragma unroll
        for (int ks = 0; ks < 2; ++ks) {
            short8 af[2], bfr[4];
            #pragma unroll
            for (int fi = 0; fi < 2; ++fi) {
                int r  = wm * 32 + fi * 16 + l15;
                int ch = ks * 4 + g4;
                af[fi] = *(const short8*)&As[r * 64 + ((ch ^ (r & 7)) << 3)];
            }
            #pragma unroll
            for (int fj = 0; fj < 4; ++fj) {
                int r  = wn * 64 + fj * 16 + l15;
                int ch = ks * 4 + g4;
                bfr[fj] = *(const short8*)&Bs[r * 64 + ((ch ^ (r & 7)) << 3)];
            }
            #pragma unroll
            for (int fi = 0; fi < 2; ++fi)
                #pragma unroll
                for (int fj = 0; fj < 4; ++fj)
                    acc[fi][fj] = __builtin_amdgcn_mfma_f32_16x16x32_bf16(af[fi], bfr[fj], acc[fi][fj], 0, 0, 0);
        }
        __syncthreads();
    }

    short* Cs = smem;
    #pragma unroll
    for (int fi = 0; fi < 2; ++fi)
        #pragma unroll
        for (int fj = 0; fj < 4; ++fj) {
            int col = wn * 64 + fj * 16 + l15;
            float bv = bias[n0 + col];
            #pragma unroll
            for (int rg = 0; rg < 4; ++rg) {
                int row = wm * 32 + fi * 16 + g4 * 4 + rg;
                float v = acc[fi][fj][rg] + bv;
                if (DO_GELU) v = gelu_sig(v);
                int ch = (col >> 3) ^ (row & 7);
                Cs[row * 128 + (ch << 3) + (col & 7)] = bfbits(v);
            }
        }
    __syncthreads();
    #pragma unroll
    for (int i = 0; i < 4; ++i) {
        int t = i * 512 + tid;
        int row = t >> 4, c16 = t & 15;
        short8 v = *(const short8*)&Cs[row * 128 + ((c16 ^ (row & 7)) << 3)];
        *(short8*)(out + (m0 + row) * (long)ldo + n0 + c16 * 8) = v;
    }
}

// ---------------- MFMA window attention ----------------
__global__ __launch_bounds__(384, 3) void attn_mfma(
    const bf16* __restrict__ qkv,
    const float* __restrict__ bias_frag,
    bf16* __restrict__ o)
{
    __shared__ __align__(16) short lds[6 * 4096];
    int tid  = threadIdx.x;
    int wave = tid >> 6;
    int lane = tid & 63;
    int h = wave;
    int w = blockIdx.x;
    int b = w >> 8, rem = w & 255;
    int wi = rem >> 4, wj = rem & 15;
    long base = (long)b * IMG_TOK + wi * 8 * 128 + wj * 8;
    int g = lane >> 4, l15 = lane & 15;

    short* Vt = &lds[wave * 4096];
    short* Ph = &lds[wave * 4096 + 2048];

    short8 qf[4], kf[4];
    #pragma unroll
    for (int fi = 0; fi < 4; ++fi) {
        int q = fi * 16 + l15;
        long t = base + (q >> 3) * 128 + (q & 7);
        const bf16* rowp = qkv + t * QKVW + h * 32 + g * 8;
        qf[fi] = *(const short8*)(rowp);
        kf[fi] = *(const short8*)(rowp + 192);
    }

    {
        int t = lane;
        const bf16* vp = qkv + (base + (t >> 3) * 128 + (t & 7)) * QKVW + 384 + h * 32;
        short8 v0 = *(const short8*)(vp);
        short8 v1 = *(const short8*)(vp + 8);
        short8 v2 = *(const short8*)(vp + 16);
        short8 v3 = *(const short8*)(vp + 24);
        int ct = t >> 3, t7 = t & 7;
        #pragma unroll
        for (int d = 0; d < 8; ++d)  Vt[d * 64 + ((ct ^ d) << 3) + t7] = v0[d];
        #pragma unroll
        for (int d = 8; d < 16; ++d) Vt[d * 64 + ((ct ^ (d & 7)) << 3) + t7] = v1[d - 8];
        #pragma unroll
        for (int d = 16; d < 24; ++d) Vt[d * 64 + ((ct ^ (d & 7)) << 3) + t7] = v2[d - 16];
        #pragma unroll
        for (int d = 24; d < 32; ++d) Vt[d * 64 + ((ct ^ (d & 7)) << 3) + t7] = v3[d - 24];
    }

    f32x4 S[4][4];
    #pragma unroll
    for (int fi = 0; fi < 4; ++fi)
        #pragma unroll
        for (int fj = 0; fj < 4; ++fj)
            S[fi][fj] = *(const f32x4*)(bias_frag + (((h * 4 + fi) * 4 + fj) * 64 + lane) * 4);
    #pragma unroll
    for (int fi = 0; fi < 4; ++fi)
        #pragma unroll
        for (int fj = 0; fj < 4; ++fj)
            S[fi][fj] = __builtin_amdgcn_mfma_f32_16x16x32_bf16(qf[fi], kf[fj], S[fi][fj], 0, 0, 0);

    f32x4 mrow[4], lsum[4];
    #pragma unroll
    for (int fi = 0; fi < 4; ++fi) {
        f32x4 a = S[fi][0], c = S[fi][2];
        #pragma unroll
        for (int cc = 0; cc < 4; ++cc) {
            a[cc] = fmaxf(a[cc], S[fi][1][cc]);
            c[cc] = fmaxf(c[cc], S[fi][3][cc]);
            a[cc] = fmaxf(a[cc], c[cc]);
        }
        mrow[fi] = a;
    }
    #pragma unroll
    for (int mask = 1; mask <= 8; mask <<= 1)
        #pragma unroll
        for (int fi = 0; fi < 4; ++fi)
            #pragma unroll
            for (int cc = 0; cc < 4; ++cc)
                mrow[fi][cc] = fmaxf(mrow[fi][cc], __shfl_xor(mrow[fi][cc], mask));
    #pragma unroll
    for (int fi = 0; fi < 4; ++fi)
        #pragma unroll
        for (int fj = 0; fj < 4; ++fj)
            #pragma unroll
            for (int cc = 0; cc < 4; ++cc)
                S[fi][fj][cc] = __expf(S[fi][fj][cc] - mrow[fi][cc]);
    #pragma unroll
    for (int fi = 0; fi < 4; ++fi) {
        f32x4 a = S[fi][0] + S[fi][1];
        f32x4 c = S[fi][2] + S[fi][3];
        lsum[fi] = a + c;
    }
    #pragma unroll
    for (int mask = 1; mask <= 8; mask <<= 1)
        #pragma unroll
        for (int fi = 0; fi < 4; ++fi)
            #pragma unroll
            for (int cc = 0; cc < 4; ++cc)
                lsum[fi][cc] += __shfl_xor(lsum[fi][cc], mask);

    f32x4 O[4][2] = {};
    #pragma unroll
    for (int ks = 0; ks < 2; ++ks) {
        #pragma unroll
        for (int fi = 0; fi < 4; ++fi)
            #pragma unroll
            for (int f2 = 0; f2 < 2; ++f2) {
                int fj = ks * 2 + f2;
                int kh = f2 * 16 + l15;
                #pragma unroll
                for (int r = 0; r < 4; ++r) {
                    int q = fi * 16 + g * 4 + r;
                    int c = (kh >> 3) ^ r ^ g;
                    Ph[q * 32 + (c << 3) + (kh & 7)] = bfbits(S[fi][fj][r]);
                }
            }
        short8 vf[2];
        #pragma unroll
        for (int f2 = 0; f2 < 2; ++f2) {
            int d = f2 * 16 + l15;
            int cv = (ks * 4 + g) ^ (d & 7);
            vf[f2] = *(const short8*)&Vt[d * 64 + (cv << 3)];
        }
        #pragma unroll
        for (int fi = 0; fi < 4; ++fi) {
            int q = fi * 16 + l15;
            int cr = g ^ (q & 3) ^ ((q >> 2) & 3);
            short8 pf = *(const short8*)&Ph[q * 32 + (cr << 3)];
            #pragma unroll
            for (int f2 = 0; f2 < 2; ++f2)
                O[fi][f2] = __builtin_amdgcn_mfma_f32_16x16x32_bf16(pf, vf[f2], O[fi][f2], 0, 0, 0);
        }
    }

    #pragma unroll
    for (int fi = 0; fi < 4; ++fi) {
        f32x4 inv;
        #pragma unroll
        for (int cc = 0; cc < 4; ++cc) inv[cc] = 1.f / lsum[fi][cc];
        #pragma unroll
        for (int r = 0; r < 4; ++r) {
            int q = fi * 16 + g * 4 + r;
            long t = base + (q >> 3) * 128 + (q & 7);
            bf16* op = o + t * CPAD + h * HD;
            op[l15] = f2bf(O[fi][0][r] * inv[r]);
            if (l15 < HD - 16)
                op[16 + l15] = f2bf(O[fi][1][r] * inv[r]);
        }
    }
    if (h == 0) {
        long t = base + (lane >> 3) * 128 + (lane & 7);
        bf16* op = o + t * CPAD + C_DIM;
        short4v z4 = {0, 0, 0, 0};
        short8  z8 = {0, 0, 0, 0, 0, 0, 0, 0};
        *(short4v*)(op) = z4;
        *(short8*)(op + 4) = z8;
    }
}

// ---------------- host launch ----------------
extern "C" void kernel_launch(void* const* d_in, const int* in_sizes, int n_in,
                              void* d_out, int out_size, void* d_ws, size_t ws_size,
                              hipStream_t stream) {
    const float* x    = (const float*)d_in[0];
    const float* n1w  = (const float*)d_in[1];
    const float* n1b  = (const float*)d_in[2];
    const float* qkvw = (const float*)d_in[3];
    const float* qkvb = (const float*)d_in[4];
    const float* tbl  = (const float*)d_in[5];
    const float* pw   = (const float*)d_in[6];
    const float* pb   = (const float*)d_in[7];
    const float* n2w  = (const float*)d_in[8];
    const float* n2b  = (const float*)d_in[9];
    const float* f1w  = (const float*)d_in[10];
    const float* f1b  = (const float*)d_in[11];
    const float* f2w  = (const float*)d_in[12];
    const float* f2b  = (const float*)d_in[13];

    auto al = [](size_t b) { return (b + 255) & ~(size_t)255; };
    char* base = (char*)d_ws;
    size_t off = 0;
    auto alloc = [&](size_t bytes) -> char* { char* p = base + off; off += al(bytes); return p; };

    bf16* wqp  = (bf16*)alloc((size_t)QKVW * CPAD * 2);
    bf16* wp   = (bf16*)alloc((size_t)192 * 192 * 2);
    bf16* wf1  = (bf16*)alloc((size_t)768 * 192 * 2);
    bf16* wf2  = (bf16*)alloc((size_t)192 * 768 * 2);
    float* bfr = (float*)alloc((size_t)6144 * 4 * 4);
    float* f1bp = (float*)alloc((size_t)HPAD * 4);
    float* qbp  = (float*)alloc((size_t)QKVW * 4);
    size_t woff = off;

    size_t r1_per = al((size_t)IMG_TOK * HPAD * 2);   // qkv[576] then h[768]
    size_t r2_per = al((size_t)IMG_TOK * CPAD * 2);   // xn -> o -> x2n
    size_t r3_per = al((size_t)IMG_TOK * C_DIM * 4);  // x1 f32
    size_t per_img = r1_per + r2_per + r3_per;
    int g = 8;
    while (g > 1 && woff + per_img * (size_t)g > ws_size) g >>= 1;
    int nchunks = 8 / g;
    long Mc = (long)IMG_TOK * g;
    int nm = (int)(Mc / 128);

    bf16*  R1 = (bf16*)(base + woff);
    bf16*  R2 = (bf16*)(base + woff + r1_per * g);
    float* R3 = (float*)(base + woff + (r1_per + r2_per) * g);

    prep_wqkv<<<(QKVW * CPAD + 255) / 256, 256, 0, stream>>>(qkvw, wqp);
    prep_bqkv<<<(QKVW + 255) / 256, 256, 0, stream>>>(qkvb, qbp);
    prep_w<<<(192 * 192 + 255) / 256, 256, 0, stream>>>(pw, wp, 180, 180, 192, 192);
    prep_w<<<(768 * 192 + 255) / 256, 256, 0, stream>>>(f1w, wf1, 180, 720, 192, 768);
    prep_w<<<(192 * 768 + 255) / 256, 256, 0, stream>>>(f2w, wf2, 720, 180, 768, 192);
    prep_bias<<<(6144 + 255) / 256, 256, 0, stream>>>(tbl, bfr);
    prep_f1b<<<(HPAD + 255) / 256, 256, 0, stream>>>(f1b, f1bp);

    for (int ci = 0; ci < nchunks; ++ci) {
        const float* xc   = x + (size_t)ci * Mc * C_DIM;
        float*       outc = (float*)d_out + (size_t)ci * Mc * C_DIM;

        // 1. LN1 -> R2 (xn)
        ln_kernel<<<Mc / 4, 256, 0, stream>>>(xc, n1w, n1b, R2, (int)Mc);
        // 2. QKV -> R1 [Mc][576], P=3 x 192-wide
        mfma_gemm192b<<<dim3(nm * 3), 512, 0, stream>>>(
            R2, CPAD, wqp, qbp, R1, QKVW, CPAD, 3);
        // 3. attention -> R2 (o)
        attn_mfma<<<dim3(256 * g), 384, 0, stream>>>(R1, bfr, R2);
        // 4. proj + residual(x f32) -> R3 (x1 f32), single 192-panel
        mfma_gemm192<<<dim3(nm), 512, 0, stream>>>(
            R2, CPAD, wp, pb, xc, 180, R3, 180, 180, CPAD);
        // 5. LN2 -> R2 (x2n)
        ln_kernel<<<Mc / 4, 256, 0, stream>>>(R3, n2w, n2b, R2, (int)Mc);
        // 6. FC1 + sigmoid-GELU -> R1 (h), P=6 x 128-wide
        mfma_gemm128<1><<<dim3(nm * 6), 512, 0, stream>>>(
            R2, CPAD, wf1, f1bp, R1, HPAD, CPAD, 6);
        // 7. FC2 + residual(x1 f32) -> out (f32), single 192-panel
        mfma_gemm192<<<dim3(nm), 512, 0, stream>>>(
            R1, HPAD, wf2, f2b, R3, 180, outc, 180, 180, HPAD);
    }
}

// Round 24
// 440.213 us; speedup vs baseline: 1.0789x; 1.0018x over previous
//
#include <hip/hip_runtime.h>
#include <hip/hip_bf16.h>

typedef __hip_bfloat16 bf16;
typedef __attribute__((ext_vector_type(8))) short short8;
typedef __attribute__((ext_vector_type(4))) short short4v;
typedef __attribute__((ext_vector_type(4))) float f32x4;

#define C_DIM 180
#define CPAD  192
#define NHEAD 6
#define HD    30
#define HID   720
#define HPAD  768
#define QKVW  576
#define LN_EPS 1e-5f
#define IMG_TOK 16384
#define QSCALE 0.18257418583505536f

static __device__ __forceinline__ bf16 f2bf(float f) { return __float2bfloat16(f); }
static __device__ __forceinline__ float bf2f(bf16 v) { return __bfloat162float(v); }
static __device__ __forceinline__ short bfbits(float f) {
    bf16 b = __float2bfloat16(f); return *reinterpret_cast<short*>(&b);
}
static __device__ __forceinline__ float gelu_sig(float v) {
    float e = __expf(-1.702f * v);
    return v * __builtin_amdgcn_rcpf(1.f + e);
}

// ---------------- weight prep ----------------
__global__ __launch_bounds__(256) void prep_w(const float* __restrict__ w, bf16* __restrict__ bt,
                                              int K, int N, int Kpad, int Npad) {
    int idx = blockIdx.x * 256 + threadIdx.x;
    if (idx >= Kpad * Npad) return;
    int k = idx % Kpad, n = idx / Kpad;
    float v = (k < K && n < N) ? w[(long)k * N + n] : 0.f;
    bt[idx] = f2bf(v);
}

__global__ __launch_bounds__(256) void prep_wqkv(const float* __restrict__ w, bf16* __restrict__ bt) {
    int idx = blockIdx.x * 256 + threadIdx.x;   // 576*192
    if (idx >= QKVW * CPAD) return;
    int k = idx % CPAD, c = idx / CPAD;
    int mat = c / 192, rem = c % 192;
    int hh = rem >> 5, dd = rem & 31;
    float v = 0.f;
    if (dd < HD && k < C_DIM) {
        v = w[(long)k * 540 + mat * 180 + hh * 30 + dd];
        if (mat == 0) v *= QSCALE;
    }
    bt[idx] = f2bf(v);
}
__global__ __launch_bounds__(256) void prep_bqkv(const float* __restrict__ b, float* __restrict__ bp) {
    int c = blockIdx.x * 256 + threadIdx.x;
    if (c >= QKVW) return;
    int mat = c / 192, rem = c % 192;
    int hh = rem >> 5, dd = rem & 31;
    float v = 0.f;
    if (dd < HD) {
        v = b[mat * 180 + hh * 30 + dd];
        if (mat == 0) v *= QSCALE;
    }
    bp[c] = v;
}

__global__ __launch_bounds__(256) void prep_f1b(const float* __restrict__ b, float* __restrict__ bp) {
    int i = blockIdx.x * 256 + threadIdx.x;
    if (i < HPAD) bp[i] = (i < HID) ? b[i] : 0.f;
}

__global__ __launch_bounds__(256) void prep_bias(const float* __restrict__ tbl,
                                                 float* __restrict__ bias_frag) {
    int idx = blockIdx.x * 256 + threadIdx.x;   // 6144
    if (idx >= 6144) return;
    int lane = idx & 63;
    int fj = (idx >> 6) & 3;
    int fi = (idx >> 8) & 3;
    int h  = idx >> 10;
    int g = lane >> 4, l15 = lane & 15;
    int kk = fj * 16 + l15;
    int rk = kk >> 3, ck = kk & 7;
    #pragma unroll
    for (int r = 0; r < 4; ++r) {
        int q = fi * 16 + g * 4 + r;
        int rq = q >> 3, cq = q & 7;
        int bidx = (rq - rk + 7) * 15 + (cq - ck + 7);
        bias_frag[idx * 4 + r] = tbl[bidx * NHEAD + h];
    }
}

// ---------------- LayerNorm ----------------
__global__ __launch_bounds__(256) void ln_kernel(const float* __restrict__ x,
                                                 const float* __restrict__ w,
                                                 const float* __restrict__ b,
                                                 bf16* __restrict__ out, int M) {
    int wave = threadIdx.x >> 6;
    int lane = threadIdx.x & 63;
    long row = (long)blockIdx.x * 4 + wave;
    if (row >= M) return;
    const float* xr = x + row * C_DIM;
    float e0 = xr[lane];
    float e1 = xr[lane + 64];
    float e2 = (lane < C_DIM - 128) ? xr[lane + 128] : 0.f;
    float s  = e0 + e1 + e2;
    float ss = e0*e0 + e1*e1 + e2*e2;
    #pragma unroll
    for (int off = 32; off > 0; off >>= 1) {
        s  += __shfl_xor(s,  off);
        ss += __shfl_xor(ss, off);
    }
    float mean = s * (1.f / C_DIM);
    float var  = ss * (1.f / C_DIM) - mean * mean;
    float rs   = rsqrtf(var + LN_EPS);
    bf16* orow = out + row * CPAD;
    orow[lane]      = f2bf((e0 - mean) * rs * w[lane]      + b[lane]);
    orow[lane + 64] = f2bf((e1 - mean) * rs * w[lane + 64] + b[lane + 64]);
    if (lane < C_DIM - 128)
        orow[lane + 128] = f2bf((e2 - mean) * rs * w[lane + 128] + b[lane + 128]);
    if (lane < CPAD - C_DIM)
        orow[C_DIM + lane] = f2bf(0.f);
}

#define GLL16(gp, lp) \
    __builtin_amdgcn_global_load_lds((const __attribute__((address_space(1))) unsigned int*)(gp), \
                                     (__attribute__((address_space(3))) unsigned int*)(lp), 16, 0, 0)

// ---------------- MFMA GEMM, 128x192 panel, 512 threads, bf16 out (QKV) ----------------
__global__ __launch_bounds__(512) void mfma_gemm192b(
    const bf16* __restrict__ A, int lda,
    const bf16* __restrict__ Bt,            // [Npad][Kpad]
    const float* __restrict__ bias,
    bf16* __restrict__ out, int ldo,
    int Kpad, int P)
{
    __shared__ __align__(16) short smem[128 * 64 + 192 * 64];   // 40 KB; epilogue reuses
    short* As = smem;
    short* Bs = smem + 128 * 64;
    int tid  = threadIdx.x;
    int lane = tid & 63;
    int wave = tid >> 6;
    int wm = wave >> 1, wn = wave & 1;
    int g4 = lane >> 4, l15 = lane & 15;

    int flat = blockIdx.x;
    int grp  = flat / (8 * P);
    int rem  = flat - grp * 8 * P;
    int p    = rem >> 3;
    long m0  = (long)(grp * 8 + (rem & 7)) * 128;
    int  n0  = p * 192;

    f32x4 acc[2][6] = {};

    int nkt = Kpad >> 6;
    for (int kt = 0; kt < nkt; ++kt) {
        int k0 = kt << 6;
        #pragma unroll
        for (int i = 0; i < 2; ++i) {
            int f = i * 512 + tid;
            int r = f >> 3, c = f & 7;
            const bf16* gp = A + (m0 + r) * (long)lda + k0 + ((c ^ (r & 7)) << 3);
            GLL16(gp, &As[(i * 512 + (wave << 6)) * 8]);
        }
        #pragma unroll
        for (int i = 0; i < 3; ++i) {
            int f = i * 512 + tid;
            int r = f >> 3, c = f & 7;
            const bf16* gp = Bt + (n0 + r) * (long)Kpad + k0 + ((c ^ (r & 7)) << 3);
            GLL16(gp, &Bs[(i * 512 + (wave << 6)) * 8]);
        }
        __syncthreads();
        #pragma unroll
        for (int ks = 0; ks < 2; ++ks) {
            short8 af[2], bfr[6];
            #pragma unroll
            for (int fi = 0; fi < 2; ++fi) {
                int r  = wm * 32 + fi * 16 + l15;
                int ch = ks * 4 + g4;
                af[fi] = *(const short8*)&As[r * 64 + ((ch ^ (r & 7)) << 3)];
            }
            #pragma unroll
            for (int fj = 0; fj < 6; ++fj) {
                int r  = wn * 96 + fj * 16 + l15;
                int ch = ks * 4 + g4;
                bfr[fj] = *(const short8*)&Bs[r * 64 + ((ch ^ (r & 7)) << 3)];
            }
            #pragma unroll
            for (int fi = 0; fi < 2; ++fi)
                #pragma unroll
                for (int fj = 0; fj < 6; ++fj)
                    acc[fi][fj] = __builtin_amdgcn_mfma_f32_16x16x32_bf16(af[fi], bfr[fj], acc[fi][fj], 0, 0, 0);
        }
        __syncthreads();
    }

    // epilogue: two 64-row phases via bf16 LDS [64][200]
    short* Cs = smem;
    #pragma unroll
    for (int ph = 0; ph < 2; ++ph) {
        if ((wm >> 1) == ph) {
            int lbase = (wm & 1) * 32;
            #pragma unroll
            for (int fi = 0; fi < 2; ++fi)
                #pragma unroll
                for (int fj = 0; fj < 6; ++fj) {
                    int col = wn * 96 + fj * 16 + l15;
                    float bv = bias[n0 + col];
                    #pragma unroll
                    for (int rg = 0; rg < 4; ++rg) {
                        int lrow = lbase + fi * 16 + g4 * 4 + rg;
                        Cs[lrow * 200 + col] = bfbits(acc[fi][fj][rg] + bv);
                    }
                }
        }
        __syncthreads();
        #pragma unroll
        for (int i = 0; i < 3; ++i) {
            int t = i * 512 + tid;
            int row = t / 24, c8 = t - row * 24;
            short8 v = *(const short8*)&Cs[row * 200 + c8 * 8];
            *(short8*)(out + (m0 + ph * 64 + row) * (long)ldo + n0 + c8 * 8) = v;
        }
        __syncthreads();
    }
}

// ---------------- MFMA GEMM, 128x192 single-panel, 512 thr, f32 out, A-dbuf (proj / FC2) ----------------
// A double-buffered (2x16KB), B single (24KB) = 56KB LDS; occupancy unchanged (VGPR-capped).
// Per tile: stageA(kt+1) issued BEFORE compute(kt) -> A's HBM latency hides under MFMA.
__global__ __launch_bounds__(512) void mfma_gemm192(
    const bf16* __restrict__ A, int lda,
    const bf16* __restrict__ Bt,            // [192][Kpad]
    const float* __restrict__ bias,
    const float* __restrict__ resid, int nres,
    float* __restrict__ out, int ldo, int nstore,
    int Kpad)
{
    __shared__ __align__(16) short smem[2 * 128 * 64 + 192 * 64];   // 32 + 24 = 56 KB
    short* Bs = smem + 2 * 128 * 64;
    int tid  = threadIdx.x;
    int lane = tid & 63;
    int wave = tid >> 6;
    int wm = wave >> 1, wn = wave & 1;
    int g4 = lane >> 4, l15 = lane & 15;

    int flat = blockIdx.x;
    long m0  = (long)flat * 128;

    auto stageA = [&](int buf, int k0) {
        #pragma unroll
        for (int i = 0; i < 2; ++i) {
            int f = i * 512 + tid;
            int r = f >> 3, c = f & 7;
            const bf16* gp = A + (m0 + r) * (long)lda + k0 + ((c ^ (r & 7)) << 3);
            GLL16(gp, &smem[(buf * 1024 + i * 512 + (wave << 6)) * 8]);
        }
    };
    auto stageB = [&](int k0) {
        #pragma unroll
        for (int i = 0; i < 3; ++i) {
            int f = i * 512 + tid;
            int r = f >> 3, c = f & 7;
            const bf16* gp = Bt + r * (long)Kpad + k0 + ((c ^ (r & 7)) << 3);
            GLL16(gp, &Bs[(i * 512 + (wave << 6)) * 8]);
        }
    };

    f32x4 acc[2][6] = {};
    int nkt = Kpad >> 6;

    stageA(0, 0);
    stageB(0);
    __syncthreads();                        // tile 0 fully staged
    int cur = 0;
    for (int kt = 0; kt < nkt; ++kt) {
        if (kt + 1 < nkt) stageA(cur ^ 1, (kt + 1) << 6);   // prefetch overlaps compute
        const short* As = smem + cur * 128 * 64;
        #pragma unroll
        for (int ks = 0; ks < 2; ++ks) {
            short8 af[2], bfr[6];
            #pragma unroll
            for (int fi = 0; fi < 2; ++fi) {
                int r  = wm * 32 + fi * 16 + l15;
                int ch = ks * 4 + g4;
                af[fi] = *(const short8*)&As[r * 64 + ((ch ^ (r & 7)) << 3)];
            }
            #pragma unroll
            for (int fj = 0; fj < 6; ++fj) {
                int r  = wn * 96 + fj * 16 + l15;
                int ch = ks * 4 + g4;
                bfr[fj] = *(const short8*)&Bs[r * 64 + ((ch ^ (r & 7)) << 3)];
            }
            #pragma unroll
            for (int fi = 0; fi < 2; ++fi)
                #pragma unroll
                for (int fj = 0; fj < 6; ++fj)
                    acc[fi][fj] = __builtin_amdgcn_mfma_f32_16x16x32_bf16(af[fi], bfr[fj], acc[fi][fj], 0, 0, 0);
        }
        __syncthreads();                    // compute reads done; A-prefetch landed
        if (kt + 1 < nkt) {
            stageB((kt + 1) << 6);          // safe: Bs reads drained above
            __syncthreads();                // B landed before next compute
        }
        cur ^= 1;
    }

    // epilogue: 4 phases of 32 rows via f32 LDS [32][196], coalesced stores + resid
    float* Cf = (float*)smem;
    int cpr = nstore >> 2;
    #pragma unroll
    for (int ph = 0; ph < 4; ++ph) {
        if (wm == ph) {
            #pragma unroll
            for (int fi = 0; fi < 2; ++fi)
                #pragma unroll
                for (int fj = 0; fj < 6; ++fj) {
                    int col = wn * 96 + fj * 16 + l15;
                    float bv = (col < nstore) ? bias[col] : 0.f;
                    #pragma unroll
                    for (int rg = 0; rg < 4; ++rg) {
                        int lrow = fi * 16 + g4 * 4 + rg;
                        Cf[lrow * 196 + col] = acc[fi][fj][rg] + bv;
                    }
                }
        }
        __syncthreads();
        for (int t = tid; t < 32 * cpr; t += 512) {
            int row = t / cpr, cc = (t - row * cpr) * 4;
            long grow = m0 + ph * 32 + row;
            f32x4 v = *(const f32x4*)&Cf[row * 196 + cc];
            if (resid) {
                f32x4 rv = *(const f32x4*)(resid + grow * (long)nres + cc);
                v += rv;
            }
            *(f32x4*)(out + grow * (long)ldo + cc) = v;
        }
        __syncthreads();
    }
}

// ---------------- MFMA GEMM, 128x128 tile, 512 threads (FC1) ----------------
template<int DO_GELU>
__global__ __launch_bounds__(512) void mfma_gemm128(
    const bf16* __restrict__ A, int lda,
    const bf16* __restrict__ Bt,
    const float* __restrict__ bias,
    bf16* __restrict__ out, int ldo,
    int Kpad, int P)
{
    __shared__ __align__(16) short smem[128 * 64 + 128 * 64];
    short* As = smem;
    short* Bs = smem + 128 * 64;
    int tid  = threadIdx.x;
    int lane = tid & 63;
    int wave = tid >> 6;
    int wm = wave >> 1, wn = wave & 1;
    int g4 = lane >> 4, l15 = lane & 15;

    int flat = blockIdx.x;
    int grp  = flat / (8 * P);
    int rem  = flat - grp * 8 * P;
    int p    = rem >> 3;
    long m0  = (long)(grp * 8 + (rem & 7)) * 128;
    int  n0  = p * 128;

    f32x4 acc[2][4] = {};

    int nkt = Kpad >> 6;
    for (int kt = 0; kt < nkt; ++kt) {
        int k0 = kt << 6;
        #pragma unroll
        for (int i = 0; i < 2; ++i) {
            int f = i * 512 + tid;
            int r = f >> 3, c = f & 7;
            const bf16* gp = A + (m0 + r) * (long)lda + k0 + ((c ^ (r & 7)) << 3);
            GLL16(gp, &As[(i * 512 + (wave << 6)) * 8]);
        }
        #pragma unroll
        for (int i = 0; i < 2; ++i) {
            int f = i * 512 + tid;
            int r = f >> 3, c = f & 7;
            const bf16* gp = Bt + (n0 + r) * (long)Kpad + k0 + ((c ^ (r & 7)) << 3);
            GLL16(gp, &Bs[(i * 512 + (wave << 6)) * 8]);
        }
        __syncthreads();
        #pragma unroll
        for (int ks = 0; ks < 2; ++ks) {
            short8 af[2], bfr[4];
            #pragma unroll
            for (int fi = 0; fi < 2; ++fi) {
                int r  = wm * 32 + fi * 16 + l15;
                int ch = ks * 4 + g4;
                af[fi] = *(const short8*)&As[r * 64 + ((ch ^ (r & 7)) << 3)];
            }
            #pragma unroll
            for (int fj = 0; fj < 4; ++fj) {
                int r  = wn * 64 + fj * 16 + l15;
                int ch = ks * 4 + g4;
                bfr[fj] = *(const short8*)&Bs[r * 64 + ((ch ^ (r & 7)) << 3)];
            }
            #pragma unroll
            for (int fi = 0; fi < 2; ++fi)
                #pragma unroll
                for (int fj = 0; fj < 4; ++fj)
                    acc[fi][fj] = __builtin_amdgcn_mfma_f32_16x16x32_bf16(af[fi], bfr[fj], acc[fi][fj], 0, 0, 0);
        }
        __syncthreads();
    }

    short* Cs = smem;
    #pragma unroll
    for (int fi = 0; fi < 2; ++fi)
        #pragma unroll
        for (int fj = 0; fj < 4; ++fj) {
            int col = wn * 64 + fj * 16 + l15;
            float bv = bias[n0 + col];
            #pragma unroll
            for (int rg = 0; rg < 4; ++rg) {
                int row = wm * 32 + fi * 16 + g4 * 4 + rg;
                float v = acc[fi][fj][rg] + bv;
                if (DO_GELU) v = gelu_sig(v);
                int ch = (col >> 3) ^ (row & 7);
                Cs[row * 128 + (ch << 3) + (col & 7)] = bfbits(v);
            }
        }
    __syncthreads();
    #pragma unroll
    for (int i = 0; i < 4; ++i) {
        int t = i * 512 + tid;
        int row = t >> 4, c16 = t & 15;
        short8 v = *(const short8*)&Cs[row * 128 + ((c16 ^ (row & 7)) << 3)];
        *(short8*)(out + (m0 + row) * (long)ldo + n0 + c16 * 8) = v;
    }
}

// ---------------- MFMA window attention ----------------
__global__ __launch_bounds__(384, 3) void attn_mfma(
    const bf16* __restrict__ qkv,
    const float* __restrict__ bias_frag,
    bf16* __restrict__ o)
{
    __shared__ __align__(16) short lds[6 * 4096];
    int tid  = threadIdx.x;
    int wave = tid >> 6;
    int lane = tid & 63;
    int h = wave;
    int w = blockIdx.x;
    int b = w >> 8, rem = w & 255;
    int wi = rem >> 4, wj = rem & 15;
    long base = (long)b * IMG_TOK + wi * 8 * 128 + wj * 8;
    int g = lane >> 4, l15 = lane & 15;

    short* Vt = &lds[wave * 4096];
    short* Ph = &lds[wave * 4096 + 2048];

    short8 qf[4], kf[4];
    #pragma unroll
    for (int fi = 0; fi < 4; ++fi) {
        int q = fi * 16 + l15;
        long t = base + (q >> 3) * 128 + (q & 7);
        const bf16* rowp = qkv + t * QKVW + h * 32 + g * 8;
        qf[fi] = *(const short8*)(rowp);
        kf[fi] = *(const short8*)(rowp + 192);
    }

    {
        int t = lane;
        const bf16* vp = qkv + (base + (t >> 3) * 128 + (t & 7)) * QKVW + 384 + h * 32;
        short8 v0 = *(const short8*)(vp);
        short8 v1 = *(const short8*)(vp + 8);
        short8 v2 = *(const short8*)(vp + 16);
        short8 v3 = *(const short8*)(vp + 24);
        int ct = t >> 3, t7 = t & 7;
        #pragma unroll
        for (int d = 0; d < 8; ++d)  Vt[d * 64 + ((ct ^ d) << 3) + t7] = v0[d];
        #pragma unroll
        for (int d = 8; d < 16; ++d) Vt[d * 64 + ((ct ^ (d & 7)) << 3) + t7] = v1[d - 8];
        #pragma unroll
        for (int d = 16; d < 24; ++d) Vt[d * 64 + ((ct ^ (d & 7)) << 3) + t7] = v2[d - 16];
        #pragma unroll
        for (int d = 24; d < 32; ++d) Vt[d * 64 + ((ct ^ (d & 7)) << 3) + t7] = v3[d - 24];
    }

    f32x4 S[4][4];
    #pragma unroll
    for (int fi = 0; fi < 4; ++fi)
        #pragma unroll
        for (int fj = 0; fj < 4; ++fj)
            S[fi][fj] = *(const f32x4*)(bias_frag + (((h * 4 + fi) * 4 + fj) * 64 + lane) * 4);
    #pragma unroll
    for (int fi = 0; fi < 4; ++fi)
        #pragma unroll
        for (int fj = 0; fj < 4; ++fj)
            S[fi][fj] = __builtin_amdgcn_mfma_f32_16x16x32_bf16(qf[fi], kf[fj], S[fi][fj], 0, 0, 0);

    f32x4 mrow[4], lsum[4];
    #pragma unroll
    for (int fi = 0; fi < 4; ++fi) {
        f32x4 a = S[fi][0], c = S[fi][2];
        #pragma unroll
        for (int cc = 0; cc < 4; ++cc) {
            a[cc] = fmaxf(a[cc], S[fi][1][cc]);
            c[cc] = fmaxf(c[cc], S[fi][3][cc]);
            a[cc] = fmaxf(a[cc], c[cc]);
        }
        mrow[fi] = a;
    }
    #pragma unroll
    for (int mask = 1; mask <= 8; mask <<= 1)
        #pragma unroll
        for (int fi = 0; fi < 4; ++fi)
            #pragma unroll
            for (int cc = 0; cc < 4; ++cc)
                mrow[fi][cc] = fmaxf(mrow[fi][cc], __shfl_xor(mrow[fi][cc], mask));
    #pragma unroll
    for (int fi = 0; fi < 4; ++fi)
        #pragma unroll
        for (int fj = 0; fj < 4; ++fj)
            #pragma unroll
            for (int cc = 0; cc < 4; ++cc)
                S[fi][fj][cc] = __expf(S[fi][fj][cc] - mrow[fi][cc]);
    #pragma unroll
    for (int fi = 0; fi < 4; ++fi) {
        f32x4 a = S[fi][0] + S[fi][1];
        f32x4 c = S[fi][2] + S[fi][3];
        lsum[fi] = a + c;
    }
    #pragma unroll
    for (int mask = 1; mask <= 8; mask <<= 1)
        #pragma unroll
        for (int fi = 0; fi < 4; ++fi)
            #pragma unroll
            for (int cc = 0; cc < 4; ++cc)
                lsum[fi][cc] += __shfl_xor(lsum[fi][cc], mask);

    f32x4 O[4][2] = {};
    #pragma unroll
    for (int ks = 0; ks < 2; ++ks) {
        #pragma unroll
        for (int fi = 0; fi < 4; ++fi)
            #pragma unroll
            for (int f2 = 0; f2 < 2; ++f2) {
                int fj = ks * 2 + f2;
                int kh = f2 * 16 + l15;
                #pragma unroll
                for (int r = 0; r < 4; ++r) {
                    int q = fi * 16 + g * 4 + r;
                    int c = (kh >> 3) ^ r ^ g;
                    Ph[q * 32 + (c << 3) + (kh & 7)] = bfbits(S[fi][fj][r]);
                }
            }
        short8 vf[2];
        #pragma unroll
        for (int f2 = 0; f2 < 2; ++f2) {
            int d = f2 * 16 + l15;
            int cv = (ks * 4 + g) ^ (d & 7);
            vf[f2] = *(const short8*)&Vt[d * 64 + (cv << 3)];
        }
        #pragma unroll
        for (int fi = 0; fi < 4; ++fi) {
            int q = fi * 16 + l15;
            int cr = g ^ (q & 3) ^ ((q >> 2) & 3);
            short8 pf = *(const short8*)&Ph[q * 32 + (cr << 3)];
            #pragma unroll
            for (int f2 = 0; f2 < 2; ++f2)
                O[fi][f2] = __builtin_amdgcn_mfma_f32_16x16x32_bf16(pf, vf[f2], O[fi][f2], 0, 0, 0);
        }
    }

    #pragma unroll
    for (int fi = 0; fi < 4; ++fi) {
        f32x4 inv;
        #pragma unroll
        for (int cc = 0; cc < 4; ++cc) inv[cc] = 1.f / lsum[fi][cc];
        #pragma unroll
        for (int r = 0; r < 4; ++r) {
            int q = fi * 16 + g * 4 + r;
            long t = base + (q >> 3) * 128 + (q & 7);
            bf16* op = o + t * CPAD + h * HD;
            op[l15] = f2bf(O[fi][0][r] * inv[r]);
            if (l15 < HD - 16)
                op[16 + l15] = f2bf(O[fi][1][r] * inv[r]);
        }
    }
    if (h == 0) {
        long t = base + (lane >> 3) * 128 + (lane & 7);
        bf16* op = o + t * CPAD + C_DIM;
        short4v z4 = {0, 0, 0, 0};
        short8  z8 = {0, 0, 0, 0, 0, 0, 0, 0};
        *(short4v*)(op) = z4;
        *(short8*)(op + 4) = z8;
    }
}

// ---------------- host launch ----------------
extern "C" void kernel_launch(void* const* d_in, const int* in_sizes, int n_in,
                              void* d_out, int out_size, void* d_ws, size_t ws_size,
                              hipStream_t stream) {
    const float* x    = (const float*)d_in[0];
    const float* n1w  = (const float*)d_in[1];
    const float* n1b  = (const float*)d_in[2];
    const float* qkvw = (const float*)d_in[3];
    const float* qkvb = (const float*)d_in[4];
    const float* tbl  = (const float*)d_in[5];
    const float* pw   = (const float*)d_in[6];
    const float* pb   = (const float*)d_in[7];
    const float* n2w  = (const float*)d_in[8];
    const float* n2b  = (const float*)d_in[9];
    const float* f1w  = (const float*)d_in[10];
    const float* f1b  = (const float*)d_in[11];
    const float* f2w  = (const float*)d_in[12];
    const float* f2b  = (const float*)d_in[13];

    auto al = [](size_t b) { return (b + 255) & ~(size_t)255; };
    char* base = (char*)d_ws;
    size_t off = 0;
    auto alloc = [&](size_t bytes) -> char* { char* p = base + off; off += al(bytes); return p; };

    bf16* wqp  = (bf16*)alloc((size_t)QKVW * CPAD * 2);
    bf16* wp   = (bf16*)alloc((size_t)192 * 192 * 2);
    bf16* wf1  = (bf16*)alloc((size_t)768 * 192 * 2);
    bf16* wf2  = (bf16*)alloc((size_t)192 * 768 * 2);
    float* bfr = (float*)alloc((size_t)6144 * 4 * 4);
    float* f1bp = (float*)alloc((size_t)HPAD * 4);
    float* qbp  = (float*)alloc((size_t)QKVW * 4);
    size_t woff = off;

    size_t r1_per = al((size_t)IMG_TOK * HPAD * 2);   // qkv[576] then h[768]
    size_t r2_per = al((size_t)IMG_TOK * CPAD * 2);   // xn -> o -> x2n
    size_t r3_per = al((size_t)IMG_TOK * C_DIM * 4);  // x1 f32
    size_t per_img = r1_per + r2_per + r3_per;
    int g = 8;
    while (g > 1 && woff + per_img * (size_t)g > ws_size) g >>= 1;
    int nchunks = 8 / g;
    long Mc = (long)IMG_TOK * g;
    int nm = (int)(Mc / 128);

    bf16*  R1 = (bf16*)(base + woff);
    bf16*  R2 = (bf16*)(base + woff + r1_per * g);
    float* R3 = (float*)(base + woff + (r1_per + r2_per) * g);

    prep_wqkv<<<(QKVW * CPAD + 255) / 256, 256, 0, stream>>>(qkvw, wqp);
    prep_bqkv<<<(QKVW + 255) / 256, 256, 0, stream>>>(qkvb, qbp);
    prep_w<<<(192 * 192 + 255) / 256, 256, 0, stream>>>(pw, wp, 180, 180, 192, 192);
    prep_w<<<(768 * 192 + 255) / 256, 256, 0, stream>>>(f1w, wf1, 180, 720, 192, 768);
    prep_w<<<(192 * 768 + 255) / 256, 256, 0, stream>>>(f2w, wf2, 720, 180, 768, 192);
    prep_bias<<<(6144 + 255) / 256, 256, 0, stream>>>(tbl, bfr);
    prep_f1b<<<(HPAD + 255) / 256, 256, 0, stream>>>(f1b, f1bp);

    for (int ci = 0; ci < nchunks; ++ci) {
        const float* xc   = x + (size_t)ci * Mc * C_DIM;
        float*       outc = (float*)d_out + (size_t)ci * Mc * C_DIM;

        // 1. LN1 -> R2 (xn)
        ln_kernel<<<Mc / 4, 256, 0, stream>>>(xc, n1w, n1b, R2, (int)Mc);
        // 2. QKV -> R1 [Mc][576], P=3 x 192-wide
        mfma_gemm192b<<<dim3(nm * 3), 512, 0, stream>>>(
            R2, CPAD, wqp, qbp, R1, QKVW, CPAD, 3);
        // 3. attention -> R2 (o)
        attn_mfma<<<dim3(256 * g), 384, 0, stream>>>(R1, bfr, R2);
        // 4. proj + residual(x f32) -> R3 (x1 f32), single 192-panel, A-dbuf
        mfma_gemm192<<<dim3(nm), 512, 0, stream>>>(
            R2, CPAD, wp, pb, xc, 180, R3, 180, 180, CPAD);
        // 5. LN2 -> R2 (x2n)
        ln_kernel<<<Mc / 4, 256, 0, stream>>>(R3, n2w, n2b, R2, (int)Mc);
        // 6. FC1 + sigmoid-GELU -> R1 (h), P=6 x 128-wide
        mfma_gemm128<1><<<dim3(nm * 6), 512, 0, stream>>>(
            R2, CPAD, wf1, f1bp, R1, HPAD, CPAD, 6);
        // 7. FC2 + residual(x1 f32) -> out (f32), single 192-panel, A-dbuf
        mfma_gemm192<<<dim3(nm), 512, 0, stream>>>(
            R1, HPAD, wf2, f2b, R3, 180, outc, 180, 180, HPAD);
    }
}